// Round 8
// baseline (679.954 us; speedup 1.0000x reference)
//
#include <hip/hip_runtime.h>
#include <hip/hip_fp16.h>
#include <math.h>

#define N_TOK 4096
#define S_LEN 2048
#define H_DIM 1024
#define E_EXP 8
#define CAPV  1536
#define NHEAD 8
#define HDHD  128

typedef __attribute__((ext_vector_type(8))) _Float16 v8h;
typedef __attribute__((ext_vector_type(4))) float v4f;
typedef __attribute__((ext_vector_type(16))) float v16f;

__device__ __forceinline__ void splitf16(float v, unsigned short& h, unsigned short& l) {
    __half hh = __float2half(v);
    h = __half_as_ushort(hh);
    l = __half_as_ushort(__float2half(v - __half2float(hh)));
}

__device__ __forceinline__ void gld_lds16(const void* g, void* l) {
    __builtin_amdgcn_global_load_lds(
        (const __attribute__((address_space(1))) unsigned int*)g,
        (__attribute__((address_space(3))) unsigned int*)l,
        16, 0, 0);
}

// ---------------------------------------------------------------- seasons
__global__ void season_k(float* seasons) {
    int s = blockIdx.x * 256 + threadIdx.x;
    if (s < S_LEN) {
        double a = (double)s * 2.0 * M_PI / 24.0;
        seasons[s] = (float)sin(a);
    }
}

__global__ void seas24_k(const float* __restrict__ seasons,
                         const float* __restrict__ Ws1, const float* __restrict__ bs1,
                         const float* __restrict__ Ws2, const float* __restrict__ bs2,
                         float* __restrict__ seas24) {
    __shared__ float hbuf[256];
    int m = blockIdx.x;
    float sv = seasons[m];
    int j = threadIdx.x;
    hbuf[j] = fmaxf(sv * Ws1[j] + bs1[j], 0.f);
    __syncthreads();
    float acc = bs2[j];
    for (int i = 0; i < 256; ++i) acc = fmaf(hbuf[i], Ws2[i * 256 + j], acc);
    seas24[m * 256 + j] = acc;
}

// ---------------------------------------------------------------- Wr2 transpose (8x1024)
__global__ void wr2t_k(const float* __restrict__ Wr2, float* __restrict__ Wr2T) {
    int i = blockIdx.x * 256 + threadIdx.x;
    int k = i >> 3, e = i & 7;
    Wr2T[e * 1024 + k] = Wr2[i];
}

// ---------------------------------------------------------------- f32 -> f16 hi/lo split
__global__ void convert_split_k(const float* __restrict__ in,
                                unsigned short* __restrict__ hi,
                                unsigned short* __restrict__ lo, int n4) {
    int i = blockIdx.x * 256 + threadIdx.x;
    if (i >= n4) return;
    float4 v = ((const float4*)in)[i];
    ushort4 h, l;
    splitf16(v.x, h.x, l.x);
    splitf16(v.y, h.y, l.y);
    splitf16(v.z, h.z, l.z);
    splitf16(v.w, h.w, l.w);
    ((ushort4*)hi)[i] = h;
    ((ushort4*)lo)[i] = l;
}

// ---------------------------------------------------------------- W[1024][1024] -> W^T hi/lo f16
__device__ __forceinline__ void wconv_body(const float* __restrict__ W,
                                           unsigned short* __restrict__ Thi,
                                           unsigned short* __restrict__ Tlo) {
    __shared__ unsigned short Hs[64][65];
    __shared__ unsigned short Ls[64][65];
    int k0 = blockIdx.y * 64, n0 = blockIdx.x * 64;
    int tid = threadIdx.x;
#pragma unroll
    for (int i = 0; i < 4; ++i) {
        int idx = tid + i * 256;
        int kk = idx >> 4, n4 = idx & 15;
        float4 v = *(const float4*)(W + (size_t)(k0 + kk) * 1024 + n0 + n4 * 4);
        unsigned short h, l;
        splitf16(v.x, h, l); Hs[n4 * 4 + 0][kk] = h; Ls[n4 * 4 + 0][kk] = l;
        splitf16(v.y, h, l); Hs[n4 * 4 + 1][kk] = h; Ls[n4 * 4 + 1][kk] = l;
        splitf16(v.z, h, l); Hs[n4 * 4 + 2][kk] = h; Ls[n4 * 4 + 2][kk] = l;
        splitf16(v.w, h, l); Hs[n4 * 4 + 3][kk] = h; Ls[n4 * 4 + 3][kk] = l;
    }
    __syncthreads();
#pragma unroll
    for (int i = 0; i < 4; ++i) {
        int idx = tid + i * 256;
        int n = idx >> 4, k4 = idx & 15;
        ushort4 h = make_ushort4(Hs[n][k4 * 4], Hs[n][k4 * 4 + 1], Hs[n][k4 * 4 + 2], Hs[n][k4 * 4 + 3]);
        ushort4 l = make_ushort4(Ls[n][k4 * 4], Ls[n][k4 * 4 + 1], Ls[n][k4 * 4 + 2], Ls[n][k4 * 4 + 3]);
        *(ushort4*)(Thi + (size_t)(n0 + n) * 1024 + k0 + k4 * 4) = h;
        *(ushort4*)(Tlo + (size_t)(n0 + n) * 1024 + k0 + k4 * 4) = l;
    }
}

__global__ __launch_bounds__(256) void wconv_t_k(const float* __restrict__ W,
                                                 unsigned short* __restrict__ Thi,
                                                 unsigned short* __restrict__ Tlo) {
    wconv_body(W, Thi, Tlo);
}

struct WBatch {
    const float* src[7];
    unsigned short* dh[7];
    unsigned short* dl[7];
};

__global__ __launch_bounds__(256) void wconv_batch_k(WBatch wb) {
    int i = blockIdx.z;
    wconv_body(wb.src[i], wb.dh[i], wb.dl[i]);
}

// ---------------------------------------------------------------- split-f16 MFMA GEMM (dbuf, unchanged from R7)
template <int MODE, int EMITF, int EMITS, int EMITT>
__global__ __launch_bounds__(256, 2) void gemm_split(
    const unsigned short* __restrict__ Ahi, const unsigned short* __restrict__ Alo,
    const unsigned short* __restrict__ WThi, const unsigned short* __restrict__ WTlo,
    const float* __restrict__ bias, float* __restrict__ Cf,
    unsigned short* __restrict__ Chi, unsigned short* __restrict__ Clo,
    const float* __restrict__ rowT, const float* __restrict__ rowS,
    const float* __restrict__ seasons, const float* __restrict__ pos,
    const float* __restrict__ seas24, float escale) {
    __shared__ unsigned short Ash[2][128 * 32];
    __shared__ unsigned short Asl[2][128 * 32];
    __shared__ unsigned short Bsh[2][64 * 32];
    __shared__ unsigned short Bsl[2][64 * 32];
    int tid = threadIdx.x;
    int lane = tid & 63, w = tid >> 6;
    int l15 = lane & 15, l16 = lane >> 4;
    int wm = (w >> 1) * 64, wn = (w & 1) * 32;
    int m0 = blockIdx.y * 128, n0 = blockIdx.x * 64;

    int ac0 = w * 128 + lane;
    int ac1 = ac0 + 64;
    int bc  = w * 64 + lane;
    int ar0 = ac0 >> 2, ar1 = ac1 >> 2, bn = bc >> 2;
    size_t a_src0 = (size_t)(m0 + ar0) * 1024 + (((ac0 & 3) ^ (ar0 & 3)) * 8);
    size_t a_src1 = (size_t)(m0 + ar1) * 1024 + (((ac1 & 3) ^ (ar1 & 3)) * 8);
    size_t b_src  = (size_t)(n0 + bn) * 1024 + (((bc & 3) ^ (bn & 3)) * 8);

    int a_off[4], b_off[2];
#pragma unroll
    for (int mi = 0; mi < 4; ++mi) {
        int row = wm + mi * 16 + l15;
        a_off[mi] = row * 32 + ((l16 ^ (row & 3)) * 8);
    }
#pragma unroll
    for (int ni = 0; ni < 2; ++ni) {
        int n = wn + ni * 16 + l15;
        b_off[ni] = n * 32 + ((l16 ^ (n & 3)) * 8);
    }

    auto STAGE = [&](int buf, int k0) {
        gld_lds16(Ahi + a_src0 + k0, &Ash[buf][ac0 * 8]);
        gld_lds16(Ahi + a_src1 + k0, &Ash[buf][ac1 * 8]);
        gld_lds16(Alo + a_src0 + k0, &Asl[buf][ac0 * 8]);
        gld_lds16(Alo + a_src1 + k0, &Asl[buf][ac1 * 8]);
        gld_lds16(WThi + b_src + k0, &Bsh[buf][bc * 8]);
        gld_lds16(WTlo + b_src + k0, &Bsl[buf][bc * 8]);
    };

    v4f acc[4][2] = {};
    STAGE(0, 0);
    __syncthreads();

    for (int kk = 0; kk < 32; ++kk) {
        int cur = kk & 1;
        if (kk < 31) STAGE(cur ^ 1, (kk + 1) * 32);
        v8h ah[4], al[4], bh[2], bl[2];
#pragma unroll
        for (int mi = 0; mi < 4; ++mi) {
            ah[mi] = *(const v8h*)&Ash[cur][a_off[mi]];
            al[mi] = *(const v8h*)&Asl[cur][a_off[mi]];
        }
#pragma unroll
        for (int ni = 0; ni < 2; ++ni) {
            bh[ni] = *(const v8h*)&Bsh[cur][b_off[ni]];
            bl[ni] = *(const v8h*)&Bsl[cur][b_off[ni]];
        }
#pragma unroll
        for (int mi = 0; mi < 4; ++mi)
#pragma unroll
            for (int ni = 0; ni < 2; ++ni) {
                acc[mi][ni] = __builtin_amdgcn_mfma_f32_16x16x32_f16(ah[mi], bh[ni], acc[mi][ni], 0, 0, 0);
                acc[mi][ni] = __builtin_amdgcn_mfma_f32_16x16x32_f16(al[mi], bh[ni], acc[mi][ni], 0, 0, 0);
                acc[mi][ni] = __builtin_amdgcn_mfma_f32_16x16x32_f16(ah[mi], bl[ni], acc[mi][ni], 0, 0, 0);
            }
        __syncthreads();
    }

    if (EMITT) {
#pragma unroll
        for (int mi = 0; mi < 4; ++mi) {
            int row0 = m0 + wm + mi * 16 + l16 * 4;
            int bb = row0 >> 11, ss = row0 & 2047;
#pragma unroll
            for (int ni = 0; ni < 2; ++ni) {
                int col = n0 + wn + ni * 16 + l15;
                int hh = col >> 7, dd = col & 127;
                size_t base = ((size_t)((bb * 8 + hh) * 128 + dd)) * 2048 + ss;
                ushort4 vh, vl;
                float v0 = acc[mi][ni][0] + bias[col];
                float v1 = acc[mi][ni][1] + bias[col];
                float v2 = acc[mi][ni][2] + bias[col];
                float v3 = acc[mi][ni][3] + bias[col];
                splitf16(v0, vh.x, vl.x);
                splitf16(v1, vh.y, vl.y);
                splitf16(v2, vh.z, vl.z);
                splitf16(v3, vh.w, vl.w);
                *(ushort4*)(Chi + base) = vh;
                *(ushort4*)(Clo + base) = vl;
            }
        }
    } else {
#pragma unroll
        for (int mi = 0; mi < 4; ++mi) {
#pragma unroll
            for (int r = 0; r < 4; ++r) {
                int row = m0 + wm + mi * 16 + l16 * 4 + r;
                int s = row & (S_LEN - 1);
                float tval = 0.f, seval = 0.f;
                if (MODE == 1) { tval = (float)s; seval = seasons[s]; }
#pragma unroll
                for (int ni = 0; ni < 2; ++ni) {
                    int col = n0 + wn + ni * 16 + l15;
                    float v = acc[mi][ni][r] + bias[col];
                    if (MODE == 1) v += tval * rowT[col] + seval * rowS[col];
                    if (MODE == 2) v += pos[(size_t)s * 1024 + col] + seas24[(s % 24) * 256 + (col & 255)];
                    if (MODE == 1 || MODE == 3) v = fmaxf(v, 0.f);
                    size_t o = (size_t)row * 1024 + col;
                    if (EMITF) Cf[o] = v;
                    if (EMITS) {
                        unsigned short hu, lu;
                        splitf16(v * escale, hu, lu);
                        Chi[o] = hu; Clo[o] = lu;
                    }
                }
            }
        }
    }
}

// ---------------------------------------------------------------- MFMA attention v3: 32x32x16
// grid (S/128, B*NH) = 256 blocks, 4 waves; wave owns 32 q-rows; KVB=64.
// K rows 256B 16-slot XOR swizzle; V hi|lo interleaved 256B rows 16-slot XOR;
// P packed u32, 8-slot XOR, phase-split (tok 0-31 then 32-63, wave-private rows).
#define ATTN_LDS_BYTES (2 * (16384 + 16384 + 32768) + 16384)   // 147456

__global__ __launch_bounds__(256, 1) void attn_mfma_k(
    const unsigned short* __restrict__ qhi, const unsigned short* __restrict__ qlo,
    const unsigned short* __restrict__ khi, const unsigned short* __restrict__ klo,
    const unsigned short* __restrict__ vthi, const unsigned short* __restrict__ vtlo,
    unsigned short* __restrict__ ctx_hi, unsigned short* __restrict__ ctx_lo) {
    extern __shared__ char smem_raw[];
    unsigned short* Ks_hi = (unsigned short*)smem_raw;       // [2][64*128]
    unsigned short* Ks_lo = Ks_hi + 2 * 8192;                // [2][64*128]
    unsigned short* Vs    = Ks_lo + 2 * 8192;                // [2][128*128] (hi|lo interleaved rows)
    unsigned int*   Ps    = (unsigned int*)(Vs + 2 * 16384); // [128*32]

    int bh = blockIdx.y;
    int b = bh >> 3, h = bh & 7;
    int q0 = blockIdx.x * 128;
    int tid = threadIdx.x;
    int lane = tid & 63, w = tid >> 6;
    int l31 = lane & 31, g = lane >> 5;

    // ---- Q A-frags (32x32x16: row=lane&31, k = ks*16 + g*8 + reg)
    v8h qa_h[8], qa_l[8];
    {
        size_t qrow = (size_t)(b * S_LEN + q0 + w * 32 + l31) * H_DIM + h * HDHD + g * 8;
#pragma unroll
        for (int ks = 0; ks < 8; ++ks) {
            qa_h[ks] = *(const v8h*)(qhi + qrow + ks * 16);
            qa_l[ks] = *(const v8h*)(qlo + qrow + ks * 16);
        }
    }

    // ---- staging addresses (pre-swizzled global sources, linear LDS dests)
    size_t kbase[4]; int kdst[4];
#pragma unroll
    for (int r = 0; r < 4; ++r) {
        int c = tid + r * 256;          // 0..1023
        int tok = c >> 4, slot = c & 15;
        kbase[r] = (size_t)(b * S_LEN + tok) * H_DIM + h * HDHD + ((slot ^ (tok & 15)) * 8);
        kdst[r] = c * 8;
    }
    const unsigned short* vsrc[8]; int vdst[8];
#pragma unroll
    for (int r = 0; r < 8; ++r) {
        int c = tid + r * 256;          // 0..2047
        int d = c >> 4, slot = c & 15;
        int logical = slot ^ (d & 15);
        int p = logical >> 3, tokc = logical & 7;
        vsrc[r] = (p ? vtlo : vthi) + (size_t)(bh * HDHD + d) * S_LEN + tokc * 8;
        vdst[r] = c * 8;
    }

    auto STAGE = [&](int buf, int kt) {
        int ko = buf * 8192, vo = buf * 16384;
        size_t koff = (size_t)kt * H_DIM;
#pragma unroll
        for (int r = 0; r < 4; ++r) {
            gld_lds16(khi + kbase[r] + koff, &Ks_hi[ko + kdst[r]]);
            gld_lds16(klo + kbase[r] + koff, &Ks_lo[ko + kdst[r]]);
        }
#pragma unroll
        for (int r = 0; r < 8; ++r)
            gld_lds16(vsrc[r] + kt, &Vs[vo + vdst[r]]);
    };

    v16f O[4] = {};
    float mreg[16], lreg[16];
#pragma unroll
    for (int i = 0; i < 16; ++i) { mreg[i] = -1e30f; lreg[i] = 0.f; }

    STAGE(0, 0);
    __syncthreads();

    for (int it = 0; it < 32; ++it) {
        int cur = it & 1;
        if (it < 31) STAGE(cur ^ 1, (it + 1) * 64);
        int ko = cur * 8192, vo = cur * 16384;

        // ---- QK^T: two 32x32 S-tiles (tok 0-31, 32-63)
        v16f s0 = {}, s1 = {};
#pragma unroll
        for (int ks = 0; ks < 8; ++ks) {
            int slot = ks * 2 + g;
#pragma unroll
            for (int j = 0; j < 2; ++j) {
                int tok = j * 32 + l31;
                int a = ko + tok * 128 + ((slot ^ (tok & 15)) * 8);
                v8h kh = *(const v8h*)&Ks_hi[a];
                v8h kl = *(const v8h*)&Ks_lo[a];
                if (j == 0) {
                    s0 = __builtin_amdgcn_mfma_f32_32x32x16_f16(qa_h[ks], kh, s0, 0, 0, 0);
                    s0 = __builtin_amdgcn_mfma_f32_32x32x16_f16(qa_l[ks], kh, s0, 0, 0, 0);
                    s0 = __builtin_amdgcn_mfma_f32_32x32x16_f16(qa_h[ks], kl, s0, 0, 0, 0);
                } else {
                    s1 = __builtin_amdgcn_mfma_f32_32x32x16_f16(qa_h[ks], kh, s1, 0, 0, 0);
                    s1 = __builtin_amdgcn_mfma_f32_32x32x16_f16(qa_l[ks], kh, s1, 0, 0, 0);
                    s1 = __builtin_amdgcn_mfma_f32_32x32x16_f16(qa_h[ks], kl, s1, 0, 0, 0);
                }
            }
        }

        // ---- online softmax (C rows: q = (i&3)+8*(i>>2)+4*g, col tok = lane&31)
        float p0a[16], p1a[16], alpha[16];
#pragma unroll
        for (int i = 0; i < 16; ++i) {
            float rm = fmaxf(s0[i], s1[i]);
            rm = fmaxf(rm, __shfl_xor(rm, 1));
            rm = fmaxf(rm, __shfl_xor(rm, 2));
            rm = fmaxf(rm, __shfl_xor(rm, 4));
            rm = fmaxf(rm, __shfl_xor(rm, 8));
            rm = fmaxf(rm, __shfl_xor(rm, 16));
            float mnew = fmaxf(mreg[i], rm);
            alpha[i] = __expf(mreg[i] - mnew);
            p0a[i] = __expf(s0[i] - mnew);
            p1a[i] = __expf(s1[i] - mnew);
            float lt = p0a[i] + p1a[i];
            lt += __shfl_xor(lt, 1);
            lt += __shfl_xor(lt, 2);
            lt += __shfl_xor(lt, 4);
            lt += __shfl_xor(lt, 8);
            lt += __shfl_xor(lt, 16);
            lreg[i] = lreg[i] * alpha[i] + lt;
            mreg[i] = mnew;
        }
#pragma unroll
        for (int t = 0; t < 4; ++t)
#pragma unroll
            for (int i = 0; i < 16; ++i) O[t][i] *= alpha[i];

        // ---- two PV phases: phase ph covers toks ph*32 .. ph*32+31
#pragma unroll
        for (int ph = 0; ph < 2; ++ph) {
            // write P (wave-private rows; no barrier needed)
#pragma unroll
            for (int i = 0; i < 16; ++i) {
                int R = w * 32 + (i & 3) + 8 * (i >> 2) + 4 * g;
                unsigned short phh, pll;
                splitf16(ph == 0 ? p0a[i] : p1a[i], phh, pll);
                int t32 = l31;
                Ps[R * 32 + ((((t32 >> 2) ^ (R & 7)) << 2) | (t32 & 3))] =
                    (unsigned)phh | ((unsigned)pll << 16);
            }
            int R = w * 32 + l31;
#pragma unroll
            for (int ks2 = 0; ks2 < 2; ++ks2) {
                int s0i = ks2 * 4 + g * 2;
                uint4 ua = *(const uint4*)&Ps[R * 32 + ((s0i ^ (R & 7)) * 4)];
                uint4 ub = *(const uint4*)&Ps[R * 32 + (((s0i + 1) ^ (R & 7)) * 4)];
                uint4 ahw, alw;
                ahw.x = (ua.x & 0xffffu) | (ua.y << 16);
                ahw.y = (ua.z & 0xffffu) | (ua.w << 16);
                ahw.z = (ub.x & 0xffffu) | (ub.y << 16);
                ahw.w = (ub.z & 0xffffu) | (ub.w << 16);
                alw.x = (ua.x >> 16) | (ua.y & 0xffff0000u);
                alw.y = (ua.z >> 16) | (ua.w & 0xffff0000u);
                alw.z = (ub.x >> 16) | (ub.y & 0xffff0000u);
                alw.w = (ub.z >> 16) | (ub.w & 0xffff0000u);
                v8h pA_h = __builtin_bit_cast(v8h, ahw);
                v8h pA_l = __builtin_bit_cast(v8h, alw);
                int gks = ph * 2 + ks2;           // global tok k-step 0..3
#pragma unroll
                for (int t = 0; t < 4; ++t) {
                    int d = t * 32 + l31;
                    int sh = gks * 2 + g;          // hi slots 0..7
                    int sl = 8 + gks * 2 + g;      // lo slots 8..15
                    v8h vh = *(const v8h*)&Vs[vo + d * 128 + ((sh ^ (d & 15)) * 8)];
                    v8h vl = *(const v8h*)&Vs[vo + d * 128 + ((sl ^ (d & 15)) * 8)];
                    O[t] = __builtin_amdgcn_mfma_f32_32x32x16_f16(pA_h, vh, O[t], 0, 0, 0);
                    O[t] = __builtin_amdgcn_mfma_f32_32x32x16_f16(pA_l, vh, O[t], 0, 0, 0);
                    O[t] = __builtin_amdgcn_mfma_f32_32x32x16_f16(pA_h, vl, O[t], 0, 0, 0);
                }
            }
        }
        __syncthreads();   // next-tile staging drained; cur reads done
    }

    // ---- epilogue
    float linv[16];
#pragma unroll
    for (int i = 0; i < 16; ++i) linv[i] = 1.f / lreg[i];
#pragma unroll
    for (int t = 0; t < 4; ++t) {
#pragma unroll
        for (int i = 0; i < 16; ++i) {
            int q = q0 + w * 32 + (i & 3) + 8 * (i >> 2) + 4 * g;
            size_t o = (size_t)(b * S_LEN + q) * H_DIM + h * HDHD + t * 32 + l31;
            unsigned short hu, lu;
            splitf16(O[t][i] * linv[i], hu, lu);
            ctx_hi[o] = hu;
            ctx_lo[o] = lu;
        }
    }
}

// ---------------------------------------------------------------- router logits (vectorized)
__global__ __launch_bounds__(256) void logits_k(const float* __restrict__ h1,
                                                const float* __restrict__ Wr2T,
                                                const float* __restrict__ br2,
                                                float* __restrict__ logits) {
    __shared__ float part[256];
    int tid = threadIdx.x;
    int tok8 = tid >> 5;
    int e = (tid >> 2) & 7;
    int ch = tid & 3;
    int tok = blockIdx.x * 8 + tok8;
    const float4* h4 = (const float4*)(h1 + (size_t)tok * 1024 + ch * 256);
    const float4* w4 = (const float4*)(Wr2T + (size_t)e * 1024 + ch * 256);
    float acc = 0.f;
#pragma unroll
    for (int i = 0; i < 64; ++i) {
        float4 a = h4[i];
        float4 bb = w4[i];
        acc = fmaf(a.x, bb.x, fmaf(a.y, bb.y, fmaf(a.z, bb.z, fmaf(a.w, bb.w, acc))));
    }
    part[tid] = acc;
    __syncthreads();
    if (ch == 0) {
        float s = part[tid] + part[tid + 1] + part[tid + 2] + part[tid + 3] + br2[e];
        logits[(size_t)tok * 8 + e] = s;
    }
}

// ---------------------------------------------------------------- fused softmax+top2+zero-fill writer
__global__ __launch_bounds__(256) void topk_fill_k(const float* __restrict__ logits,
                                                   float* __restrict__ out) {
    int tok = blockIdx.x;
    int tid = threadIdx.x;
    float l[8], p[8];
    float mx = -1e30f;
#pragma unroll
    for (int e = 0; e < 8; ++e) { l[e] = logits[(size_t)tok * 8 + e]; mx = fmaxf(mx, l[e]); }
    float sum = 0.f;
#pragma unroll
    for (int e = 0; e < 8; ++e) { p[e] = __expf(l[e] - mx); sum += p[e]; }
    float inv = 1.f / sum;
#pragma unroll
    for (int e = 0; e < 8; ++e) p[e] *= inv;
    int i1 = 0;
#pragma unroll
    for (int e = 1; e < 8; ++e) if (p[e] > p[i1]) i1 = e;
    int i2 = -1;
#pragma unroll
    for (int e = 0; e < 8; ++e) {
        if (e == i1) continue;
        if (i2 < 0 || p[e] > p[i2]) i2 = e;
    }
    float tv = p[i1] + p[i2];
    float w1 = p[i1] / tv, w2 = p[i2] / tv;

    const size_t NEC = (size_t)N_TOK * E_EXP * CAPV;
    v4f* dbase = (v4f*)(out + (size_t)tok * E_EXP * CAPV);
    v4f* cbase = (v4f*)(out + NEC + (size_t)tok * E_EXP * CAPV);
    const int NF4 = E_EXP * CAPV / 4;
#pragma unroll
    for (int it = 0; it < NF4 / 256; ++it) {
        int f = it * 256 + tid;
        int e = f / (CAPV / 4);
        int c4 = f - e * (CAPV / 4);
        v4f dv = {0.f, 0.f, 0.f, 0.f};
        v4f cv = {0.f, 0.f, 0.f, 0.f};
        if (c4 == 0) {
            if (e == i1) { dv[0] = 1.f; cv[0] = w1; }
            else if (e == i2) { dv[0] = 1.f; cv[0] = w2; }
        }
        __builtin_nontemporal_store(dv, dbase + f);
        __builtin_nontemporal_store(cv, cbase + f);
    }
    if (tid < 2) {
        float4 pv = tid == 0 ? make_float4(p[0], p[1], p[2], p[3])
                             : make_float4(p[4], p[5], p[6], p[7]);
        ((float4*)(out + 2 * NEC + (size_t)tok * 8))[tid] = pv;
    }
}

// ---------------------------------------------------------------- aux loss
__global__ void aux_k(const float* __restrict__ probs, float* __restrict__ out_aux) {
    __shared__ float part[256];
    int tid = threadIdx.x;
    int e = tid & 7, chunk = tid >> 3;
    float s = 0.f;
    for (int t = chunk * 128; t < (chunk + 1) * 128; ++t)
        s += probs[(size_t)t * 8 + e];
    part[tid] = s;
    __syncthreads();
    if (tid < 8) {
        float tot = 0.f;
        for (int c = 0; c < 32; ++c) tot += part[c * 8 + e];
        part[tid] = tot / (float)N_TOK;
    }
    __syncthreads();
    if (tid == 0) {
        float aux = 0.f;
        for (int e2 = 0; e2 < 8; ++e2) {
            float pm = part[e2];
            aux += pm * logf(pm * 8.f + 1e-9f);
        }
        *out_aux = aux;
    }
}

// ---------------------------------------------------------------- launch
extern "C" void kernel_launch(void* const* d_in, const int* in_sizes, int n_in,
                              void* d_out, int out_size, void* d_ws, size_t ws_size,
                              hipStream_t stream) {
    const float* hid = (const float*)d_in[0];
    const float* pos = (const float*)d_in[1];
    const float* We1 = (const float*)d_in[2];
    const float* be1 = (const float*)d_in[3];
    const float* We2 = (const float*)d_in[4];
    const float* be2 = (const float*)d_in[5];
    const float* Ws1 = (const float*)d_in[6];
    const float* bs1 = (const float*)d_in[7];
    const float* Ws2 = (const float*)d_in[8];
    const float* bs2 = (const float*)d_in[9];
    const float* Wq  = (const float*)d_in[10]; const float* bq = (const float*)d_in[11];
    const float* Wk  = (const float*)d_in[12]; const float* bk = (const float*)d_in[13];
    const float* Wv  = (const float*)d_in[14]; const float* bv = (const float*)d_in[15];
    const float* Wo  = (const float*)d_in[16]; const float* bo = (const float*)d_in[17];
    const float* Wr1 = (const float*)d_in[18]; const float* br1 = (const float*)d_in[19];
    const float* Wr2 = (const float*)d_in[20]; const float* br2 = (const float*)d_in[21];

    float* out = (float*)d_out;
    char* base = (char*)d_ws;
    const size_t AC  = (size_t)N_TOK * H_DIM;
    const size_t SPC = AC * 2;
    const size_t FB  = AC * 4;
    const size_t WSZ = (size_t)1024 * 1024 * 4;

    unsigned short* B1hi = (unsigned short*)(base);
    unsigned short* B1lo = (unsigned short*)(base + SPC);
    unsigned short* B2hi = (unsigned short*)(base + FB);
    unsigned short* B2lo = (unsigned short*)(base + FB + SPC);
    unsigned short* Qhi  = (unsigned short*)(base + 2 * FB);
    unsigned short* Qlo  = (unsigned short*)(base + 2 * FB + SPC);
    unsigned short* Khi  = (unsigned short*)(base + 3 * FB);
    unsigned short* Klo  = (unsigned short*)(base + 3 * FB + SPC);
    unsigned short* VThi = (unsigned short*)(base + 4 * FB);
    unsigned short* VTlo = (unsigned short*)(base + 4 * FB + SPC);
    float* h1f = (float*)(base + 3 * FB);

    char* wbase = base + 5 * FB;
    bool batched = ws_size >= 5 * FB + 7 * WSZ + (1u << 20);
    unsigned short* Whi[7];
    unsigned short* Wlo[7];
    for (int i = 0; i < 7; ++i) {
        size_t off = batched ? (size_t)i * WSZ : 0;
        Whi[i] = (unsigned short*)(wbase + off);
        Wlo[i] = (unsigned short*)(wbase + off + WSZ / 2);
    }
    char* smalls = wbase + (batched ? 7 * WSZ : WSZ);
    float* wr2t    = (float*)smalls;
    float* seas24  = wr2t + 8192;
    float* seasons = seas24 + 6144;
    float* logits  = seasons + 2048;

    const size_t NEC = (size_t)N_TOK * E_EXP * CAPV;
    const float QSCALE = 0.08838834764831845f;

    static bool attr_set = false;
    if (!attr_set) {
        hipFuncSetAttribute((const void*)attn_mfma_k,
                            hipFuncAttributeMaxDynamicSharedMemorySize,
                            ATTN_LDS_BYTES);
        attr_set = true;
    }

    dim3 gg(16, 32), blk(256);
    dim3 wg(16, 16);

    season_k<<<8, 256, 0, stream>>>(seasons);
    seas24_k<<<24, 256, 0, stream>>>(seasons, Ws1, bs1, Ws2, bs2, seas24);
    wr2t_k<<<32, 256, 0, stream>>>(Wr2, wr2t);
    convert_split_k<<<4096, 256, 0, stream>>>(hid, B1hi, B1lo, (int)(AC / 4));

    const float* wsrc[7] = {We1, We2, Wq, Wk, Wv, Wo, Wr1};
    if (batched) {
        WBatch wb;
        for (int i = 0; i < 7; ++i) { wb.src[i] = wsrc[i]; wb.dh[i] = Whi[i]; wb.dl[i] = Wlo[i]; }
        wconv_batch_k<<<dim3(16, 16, 7), blk, 0, stream>>>(wb);
    }

    auto conv = [&](int i) {
        if (!batched) wconv_t_k<<<wg, blk, 0, stream>>>(wsrc[i], Whi[i], Wlo[i]);
    };

    conv(0);
    gemm_split<1, 0, 1, 0><<<gg, blk, 0, stream>>>(B1hi, B1lo, Whi[0], Wlo[0], be1,
        nullptr, B2hi, B2lo,
        We1 + (size_t)1024 * 1024, We1 + (size_t)1025 * 1024, seasons, nullptr, nullptr, 1.f);
    conv(1);
    gemm_split<2, 0, 1, 0><<<gg, blk, 0, stream>>>(B2hi, B2lo, Whi[1], Wlo[1], be2,
        nullptr, B1hi, B1lo, nullptr, nullptr, nullptr, pos, seas24, 1.f);
    conv(2);
    gemm_split<0, 0, 1, 0><<<gg, blk, 0, stream>>>(B1hi, B1lo, Whi[2], Wlo[2], bq,
        nullptr, Qhi, Qlo, nullptr, nullptr, nullptr, nullptr, nullptr, QSCALE);
    conv(3);
    gemm_split<0, 0, 1, 0><<<gg, blk, 0, stream>>>(B1hi, B1lo, Whi[3], Wlo[3], bk,
        nullptr, Khi, Klo, nullptr, nullptr, nullptr, nullptr, nullptr, 1.f);
    conv(4);
    gemm_split<0, 0, 0, 1><<<gg, blk, 0, stream>>>(B1hi, B1lo, Whi[4], Wlo[4], bv,
        nullptr, VThi, VTlo, nullptr, nullptr, nullptr, nullptr, nullptr, 1.f);

    attn_mfma_k<<<dim3(16, 16), 256, ATTN_LDS_BYTES, stream>>>(Qhi, Qlo, Khi, Klo,
                                                               VThi, VTlo, B2hi, B2lo);

    conv(5);
    gemm_split<0, 0, 1, 0><<<gg, blk, 0, stream>>>(B2hi, B2lo, Whi[5], Wlo[5], bo,
        nullptr, B1hi, B1lo, nullptr, nullptr, nullptr, nullptr, nullptr, 1.f);
    conv(6);
    gemm_split<3, 1, 0, 0><<<gg, blk, 0, stream>>>(B1hi, B1lo, Whi[6], Wlo[6], br1,
        h1f, nullptr, nullptr, nullptr, nullptr, nullptr, nullptr, nullptr, 1.f);

    logits_k<<<512, 256, 0, stream>>>(h1f, wr2t, br2, logits);
    topk_fill_k<<<4096, 256, 0, stream>>>(logits, out);
    aux_k<<<1, 256, 0, stream>>>(out + 2 * NEC, out + 2 * NEC + (size_t)N_TOK * E_EXP);
}

// Round 9
// 616.437 us; speedup vs baseline: 1.1030x; 1.1030x over previous
//
#include <hip/hip_runtime.h>
#include <hip/hip_fp16.h>
#include <math.h>

#define N_TOK 4096
#define S_LEN 2048
#define H_DIM 1024
#define E_EXP 8
#define CAPV  1536
#define NHEAD 8
#define HDHD  128

typedef __attribute__((ext_vector_type(8))) _Float16 v8h;
typedef __attribute__((ext_vector_type(4))) float v4f;

__device__ __forceinline__ void splitf16(float v, unsigned short& h, unsigned short& l) {
    __half hh = __float2half(v);
    h = __half_as_ushort(hh);
    l = __half_as_ushort(__float2half(v - __half2float(hh)));
}

__device__ __forceinline__ void gld_lds16(const void* g, void* l) {
    __builtin_amdgcn_global_load_lds(
        (const __attribute__((address_space(1))) unsigned int*)g,
        (__attribute__((address_space(3))) unsigned int*)l,
        16, 0, 0);
}

// ---------------------------------------------------------------- fused prep:
// blocks [0,4096): hid f32->split | [4096,4104): seasons | [4104,4128): seas24
// | [4128,4160): Wr2 transpose
__global__ __launch_bounds__(256) void prep_k(
    const float* __restrict__ hid, unsigned short* __restrict__ hi,
    unsigned short* __restrict__ lo,
    const float* __restrict__ Ws1, const float* __restrict__ bs1,
    const float* __restrict__ Ws2, const float* __restrict__ bs2,
    float* __restrict__ seasons, float* __restrict__ seas24,
    const float* __restrict__ Wr2, float* __restrict__ wr2t) {
    __shared__ float hbuf[256];
    int blk = blockIdx.x;
    int tid = threadIdx.x;
    if (blk < 4096) {
        int i = blk * 256 + tid;
        float4 v = ((const float4*)hid)[i];
        ushort4 h, l;
        splitf16(v.x, h.x, l.x);
        splitf16(v.y, h.y, l.y);
        splitf16(v.z, h.z, l.z);
        splitf16(v.w, h.w, l.w);
        ((ushort4*)hi)[i] = h;
        ((ushort4*)lo)[i] = l;
    } else if (blk < 4104) {
        int s = (blk - 4096) * 256 + tid;
        if (s < S_LEN) {
            double a = (double)s * 2.0 * M_PI / 24.0;
            seasons[s] = (float)sin(a);
        }
    } else if (blk < 4128) {
        int m = blk - 4104;
        double a = (double)m * 2.0 * M_PI / 24.0;
        float sv = (float)sin(a);
        int j = tid;
        hbuf[j] = fmaxf(sv * Ws1[j] + bs1[j], 0.f);
        __syncthreads();
        float acc = bs2[j];
        for (int i = 0; i < 256; ++i) acc = fmaf(hbuf[i], Ws2[i * 256 + j], acc);
        seas24[m * 256 + j] = acc;
    } else {
        int i = (blk - 4128) * 256 + tid;
        int k = i >> 3, e = i & 7;
        wr2t[e * 1024 + k] = Wr2[i];
    }
}

// ---------------------------------------------------------------- W[1024][1024] -> W^T hi/lo f16
__device__ __forceinline__ void wconv_body(const float* __restrict__ W,
                                           unsigned short* __restrict__ Thi,
                                           unsigned short* __restrict__ Tlo) {
    __shared__ unsigned short Hs[64][65];
    __shared__ unsigned short Ls[64][65];
    int k0 = blockIdx.y * 64, n0 = blockIdx.x * 64;
    int tid = threadIdx.x;
#pragma unroll
    for (int i = 0; i < 4; ++i) {
        int idx = tid + i * 256;
        int kk = idx >> 4, n4 = idx & 15;
        float4 v = *(const float4*)(W + (size_t)(k0 + kk) * 1024 + n0 + n4 * 4);
        unsigned short h, l;
        splitf16(v.x, h, l); Hs[n4 * 4 + 0][kk] = h; Ls[n4 * 4 + 0][kk] = l;
        splitf16(v.y, h, l); Hs[n4 * 4 + 1][kk] = h; Ls[n4 * 4 + 1][kk] = l;
        splitf16(v.z, h, l); Hs[n4 * 4 + 2][kk] = h; Ls[n4 * 4 + 2][kk] = l;
        splitf16(v.w, h, l); Hs[n4 * 4 + 3][kk] = h; Ls[n4 * 4 + 3][kk] = l;
    }
    __syncthreads();
#pragma unroll
    for (int i = 0; i < 4; ++i) {
        int idx = tid + i * 256;
        int n = idx >> 4, k4 = idx & 15;
        ushort4 h = make_ushort4(Hs[n][k4 * 4], Hs[n][k4 * 4 + 1], Hs[n][k4 * 4 + 2], Hs[n][k4 * 4 + 3]);
        ushort4 l = make_ushort4(Ls[n][k4 * 4], Ls[n][k4 * 4 + 1], Ls[n][k4 * 4 + 2], Ls[n][k4 * 4 + 3]);
        *(ushort4*)(Thi + (size_t)(n0 + n) * 1024 + k0 + k4 * 4) = h;
        *(ushort4*)(Tlo + (size_t)(n0 + n) * 1024 + k0 + k4 * 4) = l;
    }
}

__global__ __launch_bounds__(256) void wconv_t_k(const float* __restrict__ W,
                                                 unsigned short* __restrict__ Thi,
                                                 unsigned short* __restrict__ Tlo) {
    wconv_body(W, Thi, Tlo);
}

struct WBatch {
    const float* src[7];
    unsigned short* dh[7];
    unsigned short* dl[7];
};

__global__ __launch_bounds__(256) void wconv_batch_k(WBatch wb) {
    int i = blockIdx.z;
    wconv_body(wb.src[i], wb.dh[i], wb.dl[i]);
}

// ---------------------------------------------------------------- split-f16 MFMA GEMM (dbuf, R7-verified)
template <int MODE, int EMITF, int EMITS, int EMITT>
__global__ __launch_bounds__(256, 2) void gemm_split(
    const unsigned short* __restrict__ Ahi, const unsigned short* __restrict__ Alo,
    const unsigned short* __restrict__ WThi, const unsigned short* __restrict__ WTlo,
    const float* __restrict__ bias, float* __restrict__ Cf,
    unsigned short* __restrict__ Chi, unsigned short* __restrict__ Clo,
    const float* __restrict__ rowT, const float* __restrict__ rowS,
    const float* __restrict__ seasons, const float* __restrict__ pos,
    const float* __restrict__ seas24, float escale) {
    __shared__ unsigned short Ash[2][128 * 32];
    __shared__ unsigned short Asl[2][128 * 32];
    __shared__ unsigned short Bsh[2][64 * 32];
    __shared__ unsigned short Bsl[2][64 * 32];
    int tid = threadIdx.x;
    int lane = tid & 63, w = tid >> 6;
    int l15 = lane & 15, l16 = lane >> 4;
    int wm = (w >> 1) * 64, wn = (w & 1) * 32;
    int m0 = blockIdx.y * 128, n0 = blockIdx.x * 64;

    int ac0 = w * 128 + lane;
    int ac1 = ac0 + 64;
    int bc  = w * 64 + lane;
    int ar0 = ac0 >> 2, ar1 = ac1 >> 2, bn = bc >> 2;
    size_t a_src0 = (size_t)(m0 + ar0) * 1024 + (((ac0 & 3) ^ (ar0 & 3)) * 8);
    size_t a_src1 = (size_t)(m0 + ar1) * 1024 + (((ac1 & 3) ^ (ar1 & 3)) * 8);
    size_t b_src  = (size_t)(n0 + bn) * 1024 + (((bc & 3) ^ (bn & 3)) * 8);

    int a_off[4], b_off[2];
#pragma unroll
    for (int mi = 0; mi < 4; ++mi) {
        int row = wm + mi * 16 + l15;
        a_off[mi] = row * 32 + ((l16 ^ (row & 3)) * 8);
    }
#pragma unroll
    for (int ni = 0; ni < 2; ++ni) {
        int n = wn + ni * 16 + l15;
        b_off[ni] = n * 32 + ((l16 ^ (n & 3)) * 8);
    }

    auto STAGE = [&](int buf, int k0) {
        gld_lds16(Ahi + a_src0 + k0, &Ash[buf][ac0 * 8]);
        gld_lds16(Ahi + a_src1 + k0, &Ash[buf][ac1 * 8]);
        gld_lds16(Alo + a_src0 + k0, &Asl[buf][ac0 * 8]);
        gld_lds16(Alo + a_src1 + k0, &Asl[buf][ac1 * 8]);
        gld_lds16(WThi + b_src + k0, &Bsh[buf][bc * 8]);
        gld_lds16(WTlo + b_src + k0, &Bsl[buf][bc * 8]);
    };

    v4f acc[4][2] = {};
    STAGE(0, 0);
    __syncthreads();

    for (int kk = 0; kk < 32; ++kk) {
        int cur = kk & 1;
        if (kk < 31) STAGE(cur ^ 1, (kk + 1) * 32);
        v8h ah[4], al[4], bh[2], bl[2];
#pragma unroll
        for (int mi = 0; mi < 4; ++mi) {
            ah[mi] = *(const v8h*)&Ash[cur][a_off[mi]];
            al[mi] = *(const v8h*)&Asl[cur][a_off[mi]];
        }
#pragma unroll
        for (int ni = 0; ni < 2; ++ni) {
            bh[ni] = *(const v8h*)&Bsh[cur][b_off[ni]];
            bl[ni] = *(const v8h*)&Bsl[cur][b_off[ni]];
        }
#pragma unroll
        for (int mi = 0; mi < 4; ++mi)
#pragma unroll
            for (int ni = 0; ni < 2; ++ni) {
                acc[mi][ni] = __builtin_amdgcn_mfma_f32_16x16x32_f16(ah[mi], bh[ni], acc[mi][ni], 0, 0, 0);
                acc[mi][ni] = __builtin_amdgcn_mfma_f32_16x16x32_f16(al[mi], bh[ni], acc[mi][ni], 0, 0, 0);
                acc[mi][ni] = __builtin_amdgcn_mfma_f32_16x16x32_f16(ah[mi], bl[ni], acc[mi][ni], 0, 0, 0);
            }
        __syncthreads();
    }

    if (EMITT) {
#pragma unroll
        for (int mi = 0; mi < 4; ++mi) {
            int row0 = m0 + wm + mi * 16 + l16 * 4;
            int bb = row0 >> 11, ss = row0 & 2047;
#pragma unroll
            for (int ni = 0; ni < 2; ++ni) {
                int col = n0 + wn + ni * 16 + l15;
                int hh = col >> 7, dd = col & 127;
                size_t base = ((size_t)((bb * 8 + hh) * 128 + dd)) * 2048 + ss;
                ushort4 vh, vl;
                float v0 = acc[mi][ni][0] + bias[col];
                float v1 = acc[mi][ni][1] + bias[col];
                float v2 = acc[mi][ni][2] + bias[col];
                float v3 = acc[mi][ni][3] + bias[col];
                splitf16(v0, vh.x, vl.x);
                splitf16(v1, vh.y, vl.y);
                splitf16(v2, vh.z, vl.z);
                splitf16(v3, vh.w, vl.w);
                *(ushort4*)(Chi + base) = vh;
                *(ushort4*)(Clo + base) = vl;
            }
        }
    } else {
#pragma unroll
        for (int mi = 0; mi < 4; ++mi) {
#pragma unroll
            for (int r = 0; r < 4; ++r) {
                int row = m0 + wm + mi * 16 + l16 * 4 + r;
                int s = row & (S_LEN - 1);
                float tval = 0.f, seval = 0.f;
                if (MODE == 1) { tval = (float)s; seval = seasons[s]; }
#pragma unroll
                for (int ni = 0; ni < 2; ++ni) {
                    int col = n0 + wn + ni * 16 + l15;
                    float v = acc[mi][ni][r] + bias[col];
                    if (MODE == 1) v += tval * rowT[col] + seval * rowS[col];
                    if (MODE == 2) v += pos[(size_t)s * 1024 + col] + seas24[(s % 24) * 256 + (col & 255)];
                    if (MODE == 1 || MODE == 3) v = fmaxf(v, 0.f);
                    size_t o = (size_t)row * 1024 + col;
                    if (EMITF) Cf[o] = v;
                    if (EMITS) {
                        unsigned short hu, lu;
                        splitf16(v * escale, hu, lu);
                        Chi[o] = hu; Clo[o] = lu;
                    }
                }
            }
        }
    }
}

// ---------------------------------------------------------------- MFMA attention v4: KV-split
// grid (32, 16, 2) = 1024 blocks; z = KV half (1024 toks, 32 iters of 32).
// Single-buffered 40KB LDS -> 4 blocks/CU (4 waves/SIMD TLP). Emits
// unnormalized partial O (f32) + per-row (m, l) for the combine pass.
__global__ __launch_bounds__(256, 4) void attn_mfma_k(
    const unsigned short* __restrict__ qhi, const unsigned short* __restrict__ qlo,
    const unsigned short* __restrict__ khi, const unsigned short* __restrict__ klo,
    const unsigned short* __restrict__ vthi, const unsigned short* __restrict__ vtlo,
    float* __restrict__ OP, float* __restrict__ ML) {
    __shared__ unsigned short Ks_hi[32 * 128];
    __shared__ unsigned short Ks_lo[32 * 128];
    __shared__ unsigned short Vs_hi[128 * 32];
    __shared__ unsigned short Vs_lo[128 * 32];
    __shared__ unsigned int   Ps[64 * 32];

    int bh = blockIdx.y;
    int b = bh >> 3, h = bh & 7;
    int q0 = blockIdx.x * 64;
    int z = blockIdx.z;
    int tid = threadIdx.x;
    int lane = tid & 63, w = tid >> 6;
    int l15 = lane & 15, l16 = lane >> 4;
    int wm = w * 16;

    v8h qa_h[4], qa_l[4];
    {
        size_t qrow = (size_t)(b * S_LEN + q0 + wm + l15) * H_DIM + h * HDHD;
#pragma unroll
        for (int ks = 0; ks < 4; ++ks) {
            qa_h[ks] = *(const v8h*)(qhi + qrow + ks * 32 + l16 * 8);
            qa_l[ks] = *(const v8h*)(qlo + qrow + ks * 32 + l16 * 8);
        }
    }

    int ktok1 = tid >> 4, kslot1 = tid & 15;
    int ktok2 = ktok1 + 16;
    size_t ksrc1 = (size_t)(b * S_LEN + ktok1) * H_DIM + h * HDHD + ((kslot1 ^ (ktok1 & 7)) * 8);
    size_t ksrc2 = (size_t)(b * S_LEN + ktok2) * H_DIM + h * HDHD + ((kslot1 ^ (ktok2 & 7)) * 8);
    int vd1 = tid >> 2, vslot1 = tid & 3;
    int vd2 = vd1 + 64;
    size_t vsrc1 = (size_t)(bh * HDHD + vd1) * S_LEN + ((vslot1 ^ ((vd1 >> 1) & 3)) * 8);
    size_t vsrc2 = (size_t)(bh * HDHD + vd2) * S_LEN + ((vslot1 ^ ((vd2 >> 1) & 3)) * 8);

    v4f accO[8] = {};
    float mreg[4] = {-1e30f, -1e30f, -1e30f, -1e30f};
    float lreg[4] = {};

    int kt0 = z * 1024;
    for (int it = 0; it < 32; ++it) {
        int kt = kt0 + it * 32;
        __syncthreads();    // prior iter's LDS reads done
        size_t koff = (size_t)kt * H_DIM;
        gld_lds16(khi + ksrc1 + koff, &Ks_hi[tid * 8]);
        gld_lds16(khi + ksrc2 + koff, &Ks_hi[(tid + 256) * 8]);
        gld_lds16(klo + ksrc1 + koff, &Ks_lo[tid * 8]);
        gld_lds16(klo + ksrc2 + koff, &Ks_lo[(tid + 256) * 8]);
        gld_lds16(vthi + vsrc1 + kt, &Vs_hi[tid * 8]);
        gld_lds16(vthi + vsrc2 + kt, &Vs_hi[(tid + 256) * 8]);
        gld_lds16(vtlo + vsrc1 + kt, &Vs_lo[tid * 8]);
        gld_lds16(vtlo + vsrc2 + kt, &Vs_lo[(tid + 256) * 8]);
        __syncthreads();    // staging complete

        // ---- QK^T: S[16 q][32 tok]
        v4f s0 = {}, s1 = {};
#pragma unroll
        for (int ks = 0; ks < 4; ++ks) {
#pragma unroll
            for (int nt = 0; nt < 2; ++nt) {
                int tok = nt * 16 + l15;
                int slot = (ks * 4 + l16) ^ (tok & 7);
                v8h bhf = *(const v8h*)&Ks_hi[tok * 128 + slot * 8];
                v8h blf = *(const v8h*)&Ks_lo[tok * 128 + slot * 8];
                v4f& ss = nt ? s1 : s0;
                ss = __builtin_amdgcn_mfma_f32_16x16x32_f16(qa_h[ks], bhf, ss, 0, 0, 0);
                ss = __builtin_amdgcn_mfma_f32_16x16x32_f16(qa_l[ks], bhf, ss, 0, 0, 0);
                ss = __builtin_amdgcn_mfma_f32_16x16x32_f16(qa_h[ks], blf, ss, 0, 0, 0);
            }
        }

        // ---- online softmax
        float p0[4], p1[4], alpha[4];
#pragma unroll
        for (int r = 0; r < 4; ++r) {
            float tmax = fmaxf(s0[r], s1[r]);
            tmax = fmaxf(tmax, __shfl_xor(tmax, 1));
            tmax = fmaxf(tmax, __shfl_xor(tmax, 2));
            tmax = fmaxf(tmax, __shfl_xor(tmax, 4));
            tmax = fmaxf(tmax, __shfl_xor(tmax, 8));
            float mnew = fmaxf(mreg[r], tmax);
            alpha[r] = __expf(mreg[r] - mnew);
            p0[r] = __expf(s0[r] - mnew);
            p1[r] = __expf(s1[r] - mnew);
            float lt = p0[r] + p1[r];
            lt += __shfl_xor(lt, 1);
            lt += __shfl_xor(lt, 2);
            lt += __shfl_xor(lt, 4);
            lt += __shfl_xor(lt, 8);
            lreg[r] = lreg[r] * alpha[r] + lt;
            mreg[r] = mnew;
        }
#pragma unroll
        for (int nt = 0; nt < 8; ++nt)
#pragma unroll
            for (int r = 0; r < 4; ++r) accO[nt][r] *= alpha[r];

        // ---- P -> Ps (wave-private rows; no barrier needed)
#pragma unroll
        for (int r = 0; r < 4; ++r) {
            int qq = wm + l16 * 4 + r;
            unsigned short ph, pl;
            splitf16(p0[r], ph, pl);
            int k0i = l15;
            Ps[qq * 32 + ((((k0i >> 2) ^ (qq & 7)) << 2) | (k0i & 3))] =
                (unsigned)ph | ((unsigned)pl << 16);
            splitf16(p1[r], ph, pl);
            int k1i = 16 + l15;
            Ps[qq * 32 + ((((k1i >> 2) ^ (qq & 7)) << 2) | (k1i & 3))] =
                (unsigned)ph | ((unsigned)pl << 16);
        }

        // ---- PV
        int qq = wm + l15;
        int sA = (l16 * 2) ^ (qq & 7);
        int sB = (l16 * 2 + 1) ^ (qq & 7);
        uint4 ua = *(const uint4*)&Ps[qq * 32 + sA * 4];
        uint4 ub = *(const uint4*)&Ps[qq * 32 + sB * 4];
        uint4 ahw, alw;
        ahw.x = (ua.x & 0xffffu) | (ua.y << 16);
        ahw.y = (ua.z & 0xffffu) | (ua.w << 16);
        ahw.z = (ub.x & 0xffffu) | (ub.y << 16);
        ahw.w = (ub.z & 0xffffu) | (ub.w << 16);
        alw.x = (ua.x >> 16) | (ua.y & 0xffff0000u);
        alw.y = (ua.z >> 16) | (ua.w & 0xffff0000u);
        alw.z = (ub.x >> 16) | (ub.y & 0xffff0000u);
        alw.w = (ub.z >> 16) | (ub.w & 0xffff0000u);
        v8h pA_h = __builtin_bit_cast(v8h, ahw);
        v8h pA_l = __builtin_bit_cast(v8h, alw);
#pragma unroll
        for (int nt = 0; nt < 8; ++nt) {
            int d = nt * 16 + l15;
            int slot = l16 ^ ((d >> 1) & 3);
            v8h vhf = *(const v8h*)&Vs_hi[d * 32 + slot * 8];
            v8h vlf = *(const v8h*)&Vs_lo[d * 32 + slot * 8];
            accO[nt] = __builtin_amdgcn_mfma_f32_16x16x32_f16(pA_h, vhf, accO[nt], 0, 0, 0);
            accO[nt] = __builtin_amdgcn_mfma_f32_16x16x32_f16(pA_l, vhf, accO[nt], 0, 0, 0);
            accO[nt] = __builtin_amdgcn_mfma_f32_16x16x32_f16(pA_h, vlf, accO[nt], 0, 0, 0);
        }
    }

    // ---- epilogue: unnormalized partials
#pragma unroll
    for (int r = 0; r < 4; ++r) {
        if (l15 == 0) {
            int q = q0 + wm + l16 * 4 + r;
            size_t mlo = ((size_t)(z * 16 + bh) * 2048 + q) * 2;
            ML[mlo] = mreg[r];
            ML[mlo + 1] = lreg[r];
        }
    }
#pragma unroll
    for (int nt = 0; nt < 8; ++nt) {
#pragma unroll
        for (int r = 0; r < 4; ++r) {
            int q = q0 + wm + l16 * 4 + r;
            size_t o = ((size_t)(z * 16 + bh) * 2048 + q) * 128 + nt * 16 + l15;
            OP[o] = accO[nt][r];
        }
    }
}

// ---------------------------------------------------------------- flash combine (2 halves -> split ctx)
__global__ __launch_bounds__(256) void attn_combine_k(
    const float* __restrict__ OP, const float* __restrict__ ML,
    unsigned short* __restrict__ ctx_hi, unsigned short* __restrict__ ctx_lo) {
    int tid = threadIdx.x;
    int R = blockIdx.x * 16 + (tid >> 4);     // 0..32767
    int bh = R >> 11, q = R & 2047;
    int b = bh >> 3, h = bh & 7;
    int d0 = (tid & 15) * 8;
    size_t ml0 = ((size_t)bh * 2048 + q) * 2;
    size_t ml1 = ((size_t)(16 + bh) * 2048 + q) * 2;
    float m0 = ML[ml0], l0 = ML[ml0 + 1];
    float m1 = ML[ml1], l1 = ML[ml1 + 1];
    float m = fmaxf(m0, m1);
    float w0 = __expf(m0 - m), w1 = __expf(m1 - m);
    float inv = 1.f / (w0 * l0 + w1 * l1);
    const float* O0 = OP + ((size_t)bh * 2048 + q) * 128 + d0;
    const float* O1 = OP + ((size_t)(16 + bh) * 2048 + q) * 128 + d0;
    size_t dst = ((size_t)(b * 2048 + q)) * 1024 + h * 128 + d0;
    float4 a0 = *(const float4*)O0;
    float4 a1 = *(const float4*)(O0 + 4);
    float4 c0 = *(const float4*)O1;
    float4 c1 = *(const float4*)(O1 + 4);
    ushort4 h0, h1, lo0, lo1;
    splitf16((w0 * a0.x + w1 * c0.x) * inv, h0.x, lo0.x);
    splitf16((w0 * a0.y + w1 * c0.y) * inv, h0.y, lo0.y);
    splitf16((w0 * a0.z + w1 * c0.z) * inv, h0.z, lo0.z);
    splitf16((w0 * a0.w + w1 * c0.w) * inv, h0.w, lo0.w);
    splitf16((w0 * a1.x + w1 * c1.x) * inv, h1.x, lo1.x);
    splitf16((w0 * a1.y + w1 * c1.y) * inv, h1.y, lo1.y);
    splitf16((w0 * a1.z + w1 * c1.z) * inv, h1.z, lo1.z);
    splitf16((w0 * a1.w + w1 * c1.w) * inv, h1.w, lo1.w);
    *(ushort4*)(ctx_hi + dst) = h0;
    *(ushort4*)(ctx_hi + dst + 4) = h1;
    *(ushort4*)(ctx_lo + dst) = lo0;
    *(ushort4*)(ctx_lo + dst + 4) = lo1;
}

// ---------------------------------------------------------------- router logits (vectorized)
__global__ __launch_bounds__(256) void logits_k(const float* __restrict__ h1,
                                                const float* __restrict__ Wr2T,
                                                const float* __restrict__ br2,
                                                float* __restrict__ logits) {
    __shared__ float part[256];
    int tid = threadIdx.x;
    int tok8 = tid >> 5;
    int e = (tid >> 2) & 7;
    int ch = tid & 3;
    int tok = blockIdx.x * 8 + tok8;
    const float4* h4 = (const float4*)(h1 + (size_t)tok * 1024 + ch * 256);
    const float4* w4 = (const float4*)(Wr2T + (size_t)e * 1024 + ch * 256);
    float acc = 0.f;
#pragma unroll
    for (int i = 0; i < 64; ++i) {
        float4 a = h4[i];
        float4 bb = w4[i];
        acc = fmaf(a.x, bb.x, fmaf(a.y, bb.y, fmaf(a.z, bb.z, fmaf(a.w, bb.w, acc))));
    }
    part[tid] = acc;
    __syncthreads();
    if (ch == 0) {
        float s = part[tid] + part[tid + 1] + part[tid + 2] + part[tid + 3] + br2[e];
        logits[(size_t)tok * 8 + e] = s;
    }
}

// ---------------------------------------------------------------- fused softmax+top2+zero-fill writer
__global__ __launch_bounds__(256) void topk_fill_k(const float* __restrict__ logits,
                                                   float* __restrict__ out) {
    int tok = blockIdx.x;
    int tid = threadIdx.x;
    float l[8], p[8];
    float mx = -1e30f;
#pragma unroll
    for (int e = 0; e < 8; ++e) { l[e] = logits[(size_t)tok * 8 + e]; mx = fmaxf(mx, l[e]); }
    float sum = 0.f;
#pragma unroll
    for (int e = 0; e < 8; ++e) { p[e] = __expf(l[e] - mx); sum += p[e]; }
    float inv = 1.f / sum;
#pragma unroll
    for (int e = 0; e < 8; ++e) p[e] *= inv;
    int i1 = 0;
#pragma unroll
    for (int e = 1; e < 8; ++e) if (p[e] > p[i1]) i1 = e;
    int i2 = -1;
#pragma unroll
    for (int e = 0; e < 8; ++e) {
        if (e == i1) continue;
        if (i2 < 0 || p[e] > p[i2]) i2 = e;
    }
    float tv = p[i1] + p[i2];
    float w1 = p[i1] / tv, w2 = p[i2] / tv;

    const size_t NEC = (size_t)N_TOK * E_EXP * CAPV;
    v4f* dbase = (v4f*)(out + (size_t)tok * E_EXP * CAPV);
    v4f* cbase = (v4f*)(out + NEC + (size_t)tok * E_EXP * CAPV);
    const int NF4 = E_EXP * CAPV / 4;
#pragma unroll
    for (int it = 0; it < NF4 / 256; ++it) {
        int f = it * 256 + tid;
        int e = f / (CAPV / 4);
        int c4 = f - e * (CAPV / 4);
        v4f dv = {0.f, 0.f, 0.f, 0.f};
        v4f cv = {0.f, 0.f, 0.f, 0.f};
        if (c4 == 0) {
            if (e == i1) { dv[0] = 1.f; cv[0] = w1; }
            else if (e == i2) { dv[0] = 1.f; cv[0] = w2; }
        }
        __builtin_nontemporal_store(dv, dbase + f);
        __builtin_nontemporal_store(cv, cbase + f);
    }
    if (tid < 2) {
        float4 pv = tid == 0 ? make_float4(p[0], p[1], p[2], p[3])
                             : make_float4(p[4], p[5], p[6], p[7]);
        ((float4*)(out + 2 * NEC + (size_t)tok * 8))[tid] = pv;
    }
}

// ---------------------------------------------------------------- aux loss
__global__ void aux_k(const float* __restrict__ probs, float* __restrict__ out_aux) {
    __shared__ float part[256];
    int tid = threadIdx.x;
    int e = tid & 7, chunk = tid >> 3;
    float s = 0.f;
    for (int t = chunk * 128; t < (chunk + 1) * 128; ++t)
        s += probs[(size_t)t * 8 + e];
    part[tid] = s;
    __syncthreads();
    if (tid < 8) {
        float tot = 0.f;
        for (int c = 0; c < 32; ++c) tot += part[c * 8 + e];
        part[tid] = tot / (float)N_TOK;
    }
    __syncthreads();
    if (tid == 0) {
        float aux = 0.f;
        for (int e2 = 0; e2 < 8; ++e2) {
            float pm = part[e2];
            aux += pm * logf(pm * 8.f + 1e-9f);
        }
        *out_aux = aux;
    }
}

// ---------------------------------------------------------------- launch
extern "C" void kernel_launch(void* const* d_in, const int* in_sizes, int n_in,
                              void* d_out, int out_size, void* d_ws, size_t ws_size,
                              hipStream_t stream) {
    const float* hid = (const float*)d_in[0];
    const float* pos = (const float*)d_in[1];
    const float* We1 = (const float*)d_in[2];
    const float* be1 = (const float*)d_in[3];
    const float* We2 = (const float*)d_in[4];
    const float* be2 = (const float*)d_in[5];
    const float* Ws1 = (const float*)d_in[6];
    const float* bs1 = (const float*)d_in[7];
    const float* Ws2 = (const float*)d_in[8];
    const float* bs2 = (const float*)d_in[9];
    const float* Wq  = (const float*)d_in[10]; const float* bq = (const float*)d_in[11];
    const float* Wk  = (const float*)d_in[12]; const float* bk = (const float*)d_in[13];
    const float* Wv  = (const float*)d_in[14]; const float* bv = (const float*)d_in[15];
    const float* Wo  = (const float*)d_in[16]; const float* bo = (const float*)d_in[17];
    const float* Wr1 = (const float*)d_in[18]; const float* br1 = (const float*)d_in[19];
    const float* Wr2 = (const float*)d_in[20]; const float* br2 = (const float*)d_in[21];

    float* out = (float*)d_out;
    char* base = (char*)d_ws;
    const size_t AC  = (size_t)N_TOK * H_DIM;
    const size_t SPC = AC * 2;
    const size_t FB  = AC * 4;
    const size_t WSZ = (size_t)1024 * 1024 * 4;

    unsigned short* B1hi = (unsigned short*)(base);
    unsigned short* B1lo = (unsigned short*)(base + SPC);
    unsigned short* B2hi = (unsigned short*)(base + FB);
    unsigned short* B2lo = (unsigned short*)(base + FB + SPC);
    unsigned short* Qhi  = (unsigned short*)(base + 2 * FB);
    unsigned short* Qlo  = (unsigned short*)(base + 2 * FB + SPC);
    unsigned short* Khi  = (unsigned short*)(base + 3 * FB);
    unsigned short* Klo  = (unsigned short*)(base + 3 * FB + SPC);
    unsigned short* VThi = (unsigned short*)(base + 4 * FB);
    unsigned short* VTlo = (unsigned short*)(base + 4 * FB + SPC);
    float* h1f = (float*)(base + 3 * FB);   // reuses K region (free after attn)

    char* wbase = base + 5 * FB;
    bool batched = ws_size >= 5 * FB + 7 * WSZ + (1u << 20);
    unsigned short* Whi[7];
    unsigned short* Wlo[7];
    for (int i = 0; i < 7; ++i) {
        size_t off = batched ? (size_t)i * WSZ : 0;
        Whi[i] = (unsigned short*)(wbase + off);
        Wlo[i] = (unsigned short*)(wbase + off + WSZ / 2);
    }
    char* smalls = wbase + (batched ? 7 * WSZ : WSZ);
    float* wr2t    = (float*)smalls;
    float* seas24  = wr2t + 8192;
    float* seasons = seas24 + 6144;
    float* logits  = seasons + 2048;

    const size_t NEC = (size_t)N_TOK * E_EXP * CAPV;
    const float QSCALE = 0.08838834764831845f;

    // attn partials scratch inside d_out's dispatch region (overwritten by topk_fill)
    float* OP = out;                                     // 2*16*2048*128 f32 = 33.5MB
    float* ML = out + (size_t)2 * 16 * 2048 * 128;       // 2*16*2048*2 f32

    dim3 gg(16, 32), blk(256);
    dim3 wg(16, 16);

    prep_k<<<4160, 256, 0, stream>>>(hid, B1hi, B1lo, Ws1, bs1, Ws2, bs2,
                                     seasons, seas24, Wr2, wr2t);

    const float* wsrc[7] = {We1, We2, Wq, Wk, Wv, Wo, Wr1};
    if (batched) {
        WBatch wb;
        for (int i = 0; i < 7; ++i) { wb.src[i] = wsrc[i]; wb.dh[i] = Whi[i]; wb.dl[i] = Wlo[i]; }
        wconv_batch_k<<<dim3(16, 16, 7), blk, 0, stream>>>(wb);
    }

    auto conv = [&](int i) {
        if (!batched) wconv_t_k<<<wg, blk, 0, stream>>>(wsrc[i], Whi[i], Wlo[i]);
    };

    conv(0);
    gemm_split<1, 0, 1, 0><<<gg, blk, 0, stream>>>(B1hi, B1lo, Whi[0], Wlo[0], be1,
        nullptr, B2hi, B2lo,
        We1 + (size_t)1024 * 1024, We1 + (size_t)1025 * 1024, seasons, nullptr, nullptr, 1.f);
    conv(1);
    gemm_split<2, 0, 1, 0><<<gg, blk, 0, stream>>>(B2hi, B2lo, Whi[1], Wlo[1], be2,
        nullptr, B1hi, B1lo, nullptr, nullptr, nullptr, pos, seas24, 1.f);
    conv(2);
    gemm_split<0, 0, 1, 0><<<gg, blk, 0, stream>>>(B1hi, B1lo, Whi[2], Wlo[2], bq,
        nullptr, Qhi, Qlo, nullptr, nullptr, nullptr, nullptr, nullptr, QSCALE);
    conv(3);
    gemm_split<0, 0, 1, 0><<<gg, blk, 0, stream>>>(B1hi, B1lo, Whi[3], Wlo[3], bk,
        nullptr, Khi, Klo, nullptr, nullptr, nullptr, nullptr, nullptr, 1.f);
    conv(4);
    gemm_split<0, 0, 0, 1><<<gg, blk, 0, stream>>>(B1hi, B1lo, Whi[4], Wlo[4], bv,
        nullptr, VThi, VTlo, nullptr, nullptr, nullptr, nullptr, nullptr, 1.f);

    attn_mfma_k<<<dim3(32, 16, 2), 256, 0, stream>>>(Qhi, Qlo, Khi, Klo,
                                                     VThi, VTlo, OP, ML);
    attn_combine_k<<<2048, 256, 0, stream>>>(OP, ML, B2hi, B2lo);

    conv(5);
    gemm_split<0, 0, 1, 0><<<gg, blk, 0, stream>>>(B2hi, B2lo, Whi[5], Wlo[5], bo,
        nullptr, B1hi, B1lo, nullptr, nullptr, nullptr, nullptr, nullptr, 1.f);
    conv(6);
    gemm_split<3, 1, 0, 0><<<gg, blk, 0, stream>>>(B1hi, B1lo, Whi[6], Wlo[6], br1,
        h1f, nullptr, nullptr, nullptr, nullptr, nullptr, nullptr, nullptr, 1.f);

    logits_k<<<512, 256, 0, stream>>>(h1f, wr2t, br2, logits);
    topk_fill_k<<<4096, 256, 0, stream>>>(logits, out);
    aux_k<<<1, 256, 0, stream>>>(out + 2 * NEC, out + 2 * NEC + (size_t)N_TOK * E_EXP);
}

// Round 10
// 610.810 us; speedup vs baseline: 1.1132x; 1.0092x over previous
//
#include <hip/hip_runtime.h>
#include <hip/hip_fp16.h>
#include <math.h>

#define N_TOK 4096
#define S_LEN 2048
#define H_DIM 1024
#define E_EXP 8
#define CAPV  1536
#define NHEAD 8
#define HDHD  128

typedef __attribute__((ext_vector_type(8))) _Float16 v8h;
typedef __attribute__((ext_vector_type(4))) float v4f;

__device__ __forceinline__ void splitf16(float v, unsigned short& h, unsigned short& l) {
    __half hh = __float2half(v);
    h = __half_as_ushort(hh);
    l = __half_as_ushort(__float2half(v - __half2float(hh)));
}

__device__ __forceinline__ void gld_lds16(const void* g, void* l) {
    __builtin_amdgcn_global_load_lds(
        (const __attribute__((address_space(1))) unsigned int*)g,
        (__attribute__((address_space(3))) unsigned int*)l,
        16, 0, 0);
}

// ---------------------------------------------------------------- fused prep
__global__ __launch_bounds__(256) void prep_k(
    const float* __restrict__ hid, unsigned short* __restrict__ hi,
    unsigned short* __restrict__ lo,
    const float* __restrict__ Ws1, const float* __restrict__ bs1,
    const float* __restrict__ Ws2, const float* __restrict__ bs2,
    float* __restrict__ seasons, float* __restrict__ seas24,
    const float* __restrict__ Wr2, float* __restrict__ wr2t) {
    __shared__ float hbuf[256];
    int blk = blockIdx.x;
    int tid = threadIdx.x;
    if (blk < 4096) {
        int i = blk * 256 + tid;
        float4 v = ((const float4*)hid)[i];
        ushort4 h, l;
        splitf16(v.x, h.x, l.x);
        splitf16(v.y, h.y, l.y);
        splitf16(v.z, h.z, l.z);
        splitf16(v.w, h.w, l.w);
        ((ushort4*)hi)[i] = h;
        ((ushort4*)lo)[i] = l;
    } else if (blk < 4104) {
        int s = (blk - 4096) * 256 + tid;
        if (s < S_LEN) {
            double a = (double)s * 2.0 * M_PI / 24.0;
            seasons[s] = (float)sin(a);
        }
    } else if (blk < 4128) {
        int m = blk - 4104;
        double a = (double)m * 2.0 * M_PI / 24.0;
        float sv = (float)sin(a);
        int j = tid;
        hbuf[j] = fmaxf(sv * Ws1[j] + bs1[j], 0.f);
        __syncthreads();
        float acc = bs2[j];
        for (int i = 0; i < 256; ++i) acc = fmaf(hbuf[i], Ws2[i * 256 + j], acc);
        seas24[m * 256 + j] = acc;
    } else {
        int i = (blk - 4128) * 256 + tid;
        int k = i >> 3, e = i & 7;
        wr2t[e * 1024 + k] = Wr2[i];
    }
}

// ---------------------------------------------------------------- W[1024][1024] -> W^T hi/lo f16
__device__ __forceinline__ void wconv_body(const float* __restrict__ W,
                                           unsigned short* __restrict__ Thi,
                                           unsigned short* __restrict__ Tlo) {
    __shared__ unsigned short Hs[64][65];
    __shared__ unsigned short Ls[64][65];
    int k0 = blockIdx.y * 64, n0 = blockIdx.x * 64;
    int tid = threadIdx.x;
#pragma unroll
    for (int i = 0; i < 4; ++i) {
        int idx = tid + i * 256;
        int kk = idx >> 4, n4 = idx & 15;
        float4 v = *(const float4*)(W + (size_t)(k0 + kk) * 1024 + n0 + n4 * 4);
        unsigned short h, l;
        splitf16(v.x, h, l); Hs[n4 * 4 + 0][kk] = h; Ls[n4 * 4 + 0][kk] = l;
        splitf16(v.y, h, l); Hs[n4 * 4 + 1][kk] = h; Ls[n4 * 4 + 1][kk] = l;
        splitf16(v.z, h, l); Hs[n4 * 4 + 2][kk] = h; Ls[n4 * 4 + 2][kk] = l;
        splitf16(v.w, h, l); Hs[n4 * 4 + 3][kk] = h; Ls[n4 * 4 + 3][kk] = l;
    }
    __syncthreads();
#pragma unroll
    for (int i = 0; i < 4; ++i) {
        int idx = tid + i * 256;
        int n = idx >> 4, k4 = idx & 15;
        ushort4 h = make_ushort4(Hs[n][k4 * 4], Hs[n][k4 * 4 + 1], Hs[n][k4 * 4 + 2], Hs[n][k4 * 4 + 3]);
        ushort4 l = make_ushort4(Ls[n][k4 * 4], Ls[n][k4 * 4 + 1], Ls[n][k4 * 4 + 2], Ls[n][k4 * 4 + 3]);
        *(ushort4*)(Thi + (size_t)(n0 + n) * 1024 + k0 + k4 * 4) = h;
        *(ushort4*)(Tlo + (size_t)(n0 + n) * 1024 + k0 + k4 * 4) = l;
    }
}

__global__ __launch_bounds__(256) void wconv_t_k(const float* __restrict__ W,
                                                 unsigned short* __restrict__ Thi,
                                                 unsigned short* __restrict__ Tlo) {
    wconv_body(W, Thi, Tlo);
}

struct WBatch {
    const float* src[7];
    unsigned short* dh[7];
    unsigned short* dl[7];
};

__global__ __launch_bounds__(256) void wconv_batch_k(WBatch wb) {
    int i = blockIdx.z;
    wconv_body(wb.src[i], wb.dh[i], wb.dl[i]);
}

// ---------------------------------------------------------------- split-f16 MFMA GEMM (dbuf + XCD swizzle)
// 1D grid 512: bid = (m%8) + 8*(n + 16*(m/8)) -> all 16 blocks of an A-panel
// share bid%8 (one XCD, 512KB panel cached in its 4MB L2).
template <int MODE, int EMITF, int EMITS, int EMITT>
__global__ __launch_bounds__(256, 2) void gemm_split(
    const unsigned short* __restrict__ Ahi, const unsigned short* __restrict__ Alo,
    const unsigned short* __restrict__ WThi, const unsigned short* __restrict__ WTlo,
    const float* __restrict__ bias, float* __restrict__ Cf,
    unsigned short* __restrict__ Chi, unsigned short* __restrict__ Clo,
    const float* __restrict__ rowT, const float* __restrict__ rowS,
    const float* __restrict__ seasons, const float* __restrict__ pos,
    const float* __restrict__ seas24, float escale) {
    __shared__ unsigned short Ash[2][128 * 32];
    __shared__ unsigned short Asl[2][128 * 32];
    __shared__ unsigned short Bsh[2][64 * 32];
    __shared__ unsigned short Bsl[2][64 * 32];
    int tid = threadIdx.x;
    int lane = tid & 63, w = tid >> 6;
    int l15 = lane & 15, l16 = lane >> 4;
    int wm = (w >> 1) * 64, wn = (w & 1) * 32;

    int bid = blockIdx.x;
    int mp = (bid & 7) + ((bid >> 7) << 3);   // 0..31
    int np = (bid >> 3) & 15;                 // 0..15
    int m0 = mp * 128, n0 = np * 64;

    int ac0 = w * 128 + lane;
    int ac1 = ac0 + 64;
    int bc  = w * 64 + lane;
    int ar0 = ac0 >> 2, ar1 = ac1 >> 2, bn = bc >> 2;
    size_t a_src0 = (size_t)(m0 + ar0) * 1024 + (((ac0 & 3) ^ (ar0 & 3)) * 8);
    size_t a_src1 = (size_t)(m0 + ar1) * 1024 + (((ac1 & 3) ^ (ar1 & 3)) * 8);
    size_t b_src  = (size_t)(n0 + bn) * 1024 + (((bc & 3) ^ (bn & 3)) * 8);

    int a_off[4], b_off[2];
#pragma unroll
    for (int mi = 0; mi < 4; ++mi) {
        int row = wm + mi * 16 + l15;
        a_off[mi] = row * 32 + ((l16 ^ (row & 3)) * 8);
    }
#pragma unroll
    for (int ni = 0; ni < 2; ++ni) {
        int n = wn + ni * 16 + l15;
        b_off[ni] = n * 32 + ((l16 ^ (n & 3)) * 8);
    }

    auto STAGE = [&](int buf, int k0) {
        gld_lds16(Ahi + a_src0 + k0, &Ash[buf][ac0 * 8]);
        gld_lds16(Ahi + a_src1 + k0, &Ash[buf][ac1 * 8]);
        gld_lds16(Alo + a_src0 + k0, &Asl[buf][ac0 * 8]);
        gld_lds16(Alo + a_src1 + k0, &Asl[buf][ac1 * 8]);
        gld_lds16(WThi + b_src + k0, &Bsh[buf][bc * 8]);
        gld_lds16(WTlo + b_src + k0, &Bsl[buf][bc * 8]);
    };

    v4f acc[4][2] = {};
    STAGE(0, 0);
    __syncthreads();

    for (int kk = 0; kk < 32; ++kk) {
        int cur = kk & 1;
        if (kk < 31) STAGE(cur ^ 1, (kk + 1) * 32);
        v8h ah[4], al[4], bh[2], bl[2];
#pragma unroll
        for (int mi = 0; mi < 4; ++mi) {
            ah[mi] = *(const v8h*)&Ash[cur][a_off[mi]];
            al[mi] = *(const v8h*)&Asl[cur][a_off[mi]];
        }
#pragma unroll
        for (int ni = 0; ni < 2; ++ni) {
            bh[ni] = *(const v8h*)&Bsh[cur][b_off[ni]];
            bl[ni] = *(const v8h*)&Bsl[cur][b_off[ni]];
        }
#pragma unroll
        for (int mi = 0; mi < 4; ++mi)
#pragma unroll
            for (int ni = 0; ni < 2; ++ni) {
                acc[mi][ni] = __builtin_amdgcn_mfma_f32_16x16x32_f16(ah[mi], bh[ni], acc[mi][ni], 0, 0, 0);
                acc[mi][ni] = __builtin_amdgcn_mfma_f32_16x16x32_f16(al[mi], bh[ni], acc[mi][ni], 0, 0, 0);
                acc[mi][ni] = __builtin_amdgcn_mfma_f32_16x16x32_f16(ah[mi], bl[ni], acc[mi][ni], 0, 0, 0);
            }
        __syncthreads();
    }

    if (EMITT) {
#pragma unroll
        for (int mi = 0; mi < 4; ++mi) {
            int row0 = m0 + wm + mi * 16 + l16 * 4;
            int bb = row0 >> 11, ss = row0 & 2047;
#pragma unroll
            for (int ni = 0; ni < 2; ++ni) {
                int col = n0 + wn + ni * 16 + l15;
                int hh = col >> 7, dd = col & 127;
                size_t base = ((size_t)((bb * 8 + hh) * 128 + dd)) * 2048 + ss;
                ushort4 vh, vl;
                float v0 = acc[mi][ni][0] + bias[col];
                float v1 = acc[mi][ni][1] + bias[col];
                float v2 = acc[mi][ni][2] + bias[col];
                float v3 = acc[mi][ni][3] + bias[col];
                splitf16(v0, vh.x, vl.x);
                splitf16(v1, vh.y, vl.y);
                splitf16(v2, vh.z, vl.z);
                splitf16(v3, vh.w, vl.w);
                *(ushort4*)(Chi + base) = vh;
                *(ushort4*)(Clo + base) = vl;
            }
        }
    } else {
#pragma unroll
        for (int mi = 0; mi < 4; ++mi) {
#pragma unroll
            for (int r = 0; r < 4; ++r) {
                int row = m0 + wm + mi * 16 + l16 * 4 + r;
                int s = row & (S_LEN - 1);
                float tval = 0.f, seval = 0.f;
                if (MODE == 1) { tval = (float)s; seval = seasons[s]; }
#pragma unroll
                for (int ni = 0; ni < 2; ++ni) {
                    int col = n0 + wn + ni * 16 + l15;
                    float v = acc[mi][ni][r] + bias[col];
                    if (MODE == 1) v += tval * rowT[col] + seval * rowS[col];
                    if (MODE == 2) v += pos[(size_t)s * 1024 + col] + seas24[(s % 24) * 256 + (col & 255)];
                    if (MODE == 1 || MODE == 3) v = fmaxf(v, 0.f);
                    size_t o = (size_t)row * 1024 + col;
                    if (EMITF) Cf[o] = v;
                    if (EMITS) {
                        unsigned short hu, lu;
                        splitf16(v * escale, hu, lu);
                        Chi[o] = hu; Clo[o] = lu;
                    }
                }
            }
        }
    }
}

// ---------------------------------------------------------------- MFMA attention v4 + XCD swizzle
// 1D grid 1024: group g = bh*2+z (32 groups of 32 q-blocks); all blocks of a
// group share bid%8 -> one XCD; its 1MB K/V half lives in that L2.
__global__ __launch_bounds__(256, 4) void attn_mfma_k(
    const unsigned short* __restrict__ qhi, const unsigned short* __restrict__ qlo,
    const unsigned short* __restrict__ khi, const unsigned short* __restrict__ klo,
    const unsigned short* __restrict__ vthi, const unsigned short* __restrict__ vtlo,
    float* __restrict__ OP, float* __restrict__ ML) {
    __shared__ unsigned short Ks_hi[32 * 128];
    __shared__ unsigned short Ks_lo[32 * 128];
    __shared__ unsigned short Vs_hi[128 * 32];
    __shared__ unsigned short Vs_lo[128 * 32];
    __shared__ unsigned int   Ps[64 * 32];

    int p = blockIdx.x;
    int x = (p >> 3) & 31;
    int g = (p & 7) + ((p >> 8) << 3);    // 0..31
    int bh = g >> 1, z = g & 1;
    int b = bh >> 3, h = bh & 7;
    int q0 = x * 64;
    int tid = threadIdx.x;
    int lane = tid & 63, w = tid >> 6;
    int l15 = lane & 15, l16 = lane >> 4;
    int wm = w * 16;

    v8h qa_h[4], qa_l[4];
    {
        size_t qrow = (size_t)(b * S_LEN + q0 + wm + l15) * H_DIM + h * HDHD;
#pragma unroll
        for (int ks = 0; ks < 4; ++ks) {
            qa_h[ks] = *(const v8h*)(qhi + qrow + ks * 32 + l16 * 8);
            qa_l[ks] = *(const v8h*)(qlo + qrow + ks * 32 + l16 * 8);
        }
    }

    int ktok1 = tid >> 4, kslot1 = tid & 15;
    int ktok2 = ktok1 + 16;
    size_t ksrc1 = (size_t)(b * S_LEN + ktok1) * H_DIM + h * HDHD + ((kslot1 ^ (ktok1 & 7)) * 8);
    size_t ksrc2 = (size_t)(b * S_LEN + ktok2) * H_DIM + h * HDHD + ((kslot1 ^ (ktok2 & 7)) * 8);
    int vd1 = tid >> 2, vslot1 = tid & 3;
    int vd2 = vd1 + 64;
    size_t vsrc1 = (size_t)(bh * HDHD + vd1) * S_LEN + ((vslot1 ^ ((vd1 >> 1) & 3)) * 8);
    size_t vsrc2 = (size_t)(bh * HDHD + vd2) * S_LEN + ((vslot1 ^ ((vd2 >> 1) & 3)) * 8);

    v4f accO[8] = {};
    float mreg[4] = {-1e30f, -1e30f, -1e30f, -1e30f};
    float lreg[4] = {};

    int kt0 = z * 1024;
    for (int it = 0; it < 32; ++it) {
        int kt = kt0 + it * 32;
        __syncthreads();
        size_t koff = (size_t)kt * H_DIM;
        gld_lds16(khi + ksrc1 + koff, &Ks_hi[tid * 8]);
        gld_lds16(khi + ksrc2 + koff, &Ks_hi[(tid + 256) * 8]);
        gld_lds16(klo + ksrc1 + koff, &Ks_lo[tid * 8]);
        gld_lds16(klo + ksrc2 + koff, &Ks_lo[(tid + 256) * 8]);
        gld_lds16(vthi + vsrc1 + kt, &Vs_hi[tid * 8]);
        gld_lds16(vthi + vsrc2 + kt, &Vs_hi[(tid + 256) * 8]);
        gld_lds16(vtlo + vsrc1 + kt, &Vs_lo[tid * 8]);
        gld_lds16(vtlo + vsrc2 + kt, &Vs_lo[(tid + 256) * 8]);
        __syncthreads();

        v4f s0 = {}, s1 = {};
#pragma unroll
        for (int ks = 0; ks < 4; ++ks) {
#pragma unroll
            for (int nt = 0; nt < 2; ++nt) {
                int tok = nt * 16 + l15;
                int slot = (ks * 4 + l16) ^ (tok & 7);
                v8h bhf = *(const v8h*)&Ks_hi[tok * 128 + slot * 8];
                v8h blf = *(const v8h*)&Ks_lo[tok * 128 + slot * 8];
                v4f& ss = nt ? s1 : s0;
                ss = __builtin_amdgcn_mfma_f32_16x16x32_f16(qa_h[ks], bhf, ss, 0, 0, 0);
                ss = __builtin_amdgcn_mfma_f32_16x16x32_f16(qa_l[ks], bhf, ss, 0, 0, 0);
                ss = __builtin_amdgcn_mfma_f32_16x16x32_f16(qa_h[ks], blf, ss, 0, 0, 0);
            }
        }

        float p0[4], p1[4], alpha[4];
#pragma unroll
        for (int r = 0; r < 4; ++r) {
            float tmax = fmaxf(s0[r], s1[r]);
            tmax = fmaxf(tmax, __shfl_xor(tmax, 1));
            tmax = fmaxf(tmax, __shfl_xor(tmax, 2));
            tmax = fmaxf(tmax, __shfl_xor(tmax, 4));
            tmax = fmaxf(tmax, __shfl_xor(tmax, 8));
            float mnew = fmaxf(mreg[r], tmax);
            alpha[r] = __expf(mreg[r] - mnew);
            p0[r] = __expf(s0[r] - mnew);
            p1[r] = __expf(s1[r] - mnew);
            float lt = p0[r] + p1[r];
            lt += __shfl_xor(lt, 1);
            lt += __shfl_xor(lt, 2);
            lt += __shfl_xor(lt, 4);
            lt += __shfl_xor(lt, 8);
            lreg[r] = lreg[r] * alpha[r] + lt;
            mreg[r] = mnew;
        }
#pragma unroll
        for (int nt = 0; nt < 8; ++nt)
#pragma unroll
            for (int r = 0; r < 4; ++r) accO[nt][r] *= alpha[r];

#pragma unroll
        for (int r = 0; r < 4; ++r) {
            int qq = wm + l16 * 4 + r;
            unsigned short ph, pl;
            splitf16(p0[r], ph, pl);
            int k0i = l15;
            Ps[qq * 32 + ((((k0i >> 2) ^ (qq & 7)) << 2) | (k0i & 3))] =
                (unsigned)ph | ((unsigned)pl << 16);
            splitf16(p1[r], ph, pl);
            int k1i = 16 + l15;
            Ps[qq * 32 + ((((k1i >> 2) ^ (qq & 7)) << 2) | (k1i & 3))] =
                (unsigned)ph | ((unsigned)pl << 16);
        }

        int qq = wm + l15;
        int sA = (l16 * 2) ^ (qq & 7);
        int sB = (l16 * 2 + 1) ^ (qq & 7);
        uint4 ua = *(const uint4*)&Ps[qq * 32 + sA * 4];
        uint4 ub = *(const uint4*)&Ps[qq * 32 + sB * 4];
        uint4 ahw, alw;
        ahw.x = (ua.x & 0xffffu) | (ua.y << 16);
        ahw.y = (ua.z & 0xffffu) | (ua.w << 16);
        ahw.z = (ub.x & 0xffffu) | (ub.y << 16);
        ahw.w = (ub.z & 0xffffu) | (ub.w << 16);
        alw.x = (ua.x >> 16) | (ua.y & 0xffff0000u);
        alw.y = (ua.z >> 16) | (ua.w & 0xffff0000u);
        alw.z = (ub.x >> 16) | (ub.y & 0xffff0000u);
        alw.w = (ub.z >> 16) | (ub.w & 0xffff0000u);
        v8h pA_h = __builtin_bit_cast(v8h, ahw);
        v8h pA_l = __builtin_bit_cast(v8h, alw);
#pragma unroll
        for (int nt = 0; nt < 8; ++nt) {
            int d = nt * 16 + l15;
            int slot = l16 ^ ((d >> 1) & 3);
            v8h vhf = *(const v8h*)&Vs_hi[d * 32 + slot * 8];
            v8h vlf = *(const v8h*)&Vs_lo[d * 32 + slot * 8];
            accO[nt] = __builtin_amdgcn_mfma_f32_16x16x32_f16(pA_h, vhf, accO[nt], 0, 0, 0);
            accO[nt] = __builtin_amdgcn_mfma_f32_16x16x32_f16(pA_l, vhf, accO[nt], 0, 0, 0);
            accO[nt] = __builtin_amdgcn_mfma_f32_16x16x32_f16(pA_h, vlf, accO[nt], 0, 0, 0);
        }
    }

#pragma unroll
    for (int r = 0; r < 4; ++r) {
        if (l15 == 0) {
            int q = q0 + wm + l16 * 4 + r;
            size_t mlo = ((size_t)(z * 16 + bh) * 2048 + q) * 2;
            ML[mlo] = mreg[r];
            ML[mlo + 1] = lreg[r];
        }
    }
#pragma unroll
    for (int nt = 0; nt < 8; ++nt) {
#pragma unroll
        for (int r = 0; r < 4; ++r) {
            int q = q0 + wm + l16 * 4 + r;
            size_t o = ((size_t)(z * 16 + bh) * 2048 + q) * 128 + nt * 16 + l15;
            OP[o] = accO[nt][r];
        }
    }
}

// ---------------------------------------------------------------- flash combine
__global__ __launch_bounds__(256) void attn_combine_k(
    const float* __restrict__ OP, const float* __restrict__ ML,
    unsigned short* __restrict__ ctx_hi, unsigned short* __restrict__ ctx_lo) {
    int tid = threadIdx.x;
    int R = blockIdx.x * 16 + (tid >> 4);
    int bh = R >> 11, q = R & 2047;
    int b = bh >> 3, h = bh & 7;
    int d0 = (tid & 15) * 8;
    size_t ml0 = ((size_t)bh * 2048 + q) * 2;
    size_t ml1 = ((size_t)(16 + bh) * 2048 + q) * 2;
    float m0 = ML[ml0], l0 = ML[ml0 + 1];
    float m1 = ML[ml1], l1 = ML[ml1 + 1];
    float m = fmaxf(m0, m1);
    float w0 = __expf(m0 - m), w1 = __expf(m1 - m);
    float inv = 1.f / (w0 * l0 + w1 * l1);
    const float* O0 = OP + ((size_t)bh * 2048 + q) * 128 + d0;
    const float* O1 = OP + ((size_t)(16 + bh) * 2048 + q) * 128 + d0;
    size_t dst = ((size_t)(b * 2048 + q)) * 1024 + h * 128 + d0;
    float4 a0 = *(const float4*)O0;
    float4 a1 = *(const float4*)(O0 + 4);
    float4 c0 = *(const float4*)O1;
    float4 c1 = *(const float4*)(O1 + 4);
    ushort4 h0, h1, lo0, lo1;
    splitf16((w0 * a0.x + w1 * c0.x) * inv, h0.x, lo0.x);
    splitf16((w0 * a0.y + w1 * c0.y) * inv, h0.y, lo0.y);
    splitf16((w0 * a0.z + w1 * c0.z) * inv, h0.z, lo0.z);
    splitf16((w0 * a0.w + w1 * c0.w) * inv, h0.w, lo0.w);
    splitf16((w0 * a1.x + w1 * c1.x) * inv, h1.x, lo1.x);
    splitf16((w0 * a1.y + w1 * c1.y) * inv, h1.y, lo1.y);
    splitf16((w0 * a1.z + w1 * c1.z) * inv, h1.z, lo1.z);
    splitf16((w0 * a1.w + w1 * c1.w) * inv, h1.w, lo1.w);
    *(ushort4*)(ctx_hi + dst) = h0;
    *(ushort4*)(ctx_hi + dst + 4) = h1;
    *(ushort4*)(ctx_lo + dst) = lo0;
    *(ushort4*)(ctx_lo + dst + 4) = lo1;
}

// ---------------------------------------------------------------- router logits
__global__ __launch_bounds__(256) void logits_k(const float* __restrict__ h1,
                                                const float* __restrict__ Wr2T,
                                                const float* __restrict__ br2,
                                                float* __restrict__ logits) {
    __shared__ float part[256];
    int tid = threadIdx.x;
    int tok8 = tid >> 5;
    int e = (tid >> 2) & 7;
    int ch = tid & 3;
    int tok = blockIdx.x * 8 + tok8;
    const float4* h4 = (const float4*)(h1 + (size_t)tok * 1024 + ch * 256);
    const float4* w4 = (const float4*)(Wr2T + (size_t)e * 1024 + ch * 256);
    float acc = 0.f;
#pragma unroll
    for (int i = 0; i < 64; ++i) {
        float4 a = h4[i];
        float4 bb = w4[i];
        acc = fmaf(a.x, bb.x, fmaf(a.y, bb.y, fmaf(a.z, bb.z, fmaf(a.w, bb.w, acc))));
    }
    part[tid] = acc;
    __syncthreads();
    if (ch == 0) {
        float s = part[tid] + part[tid + 1] + part[tid + 2] + part[tid + 3] + br2[e];
        logits[(size_t)tok * 8 + e] = s;
    }
}

// ---------------------------------------------------------------- fused softmax+top2+zero-fill writer
__global__ __launch_bounds__(256) void topk_fill_k(const float* __restrict__ logits,
                                                   float* __restrict__ out) {
    int tok = blockIdx.x;
    int tid = threadIdx.x;
    float l[8], p[8];
    float mx = -1e30f;
#pragma unroll
    for (int e = 0; e < 8; ++e) { l[e] = logits[(size_t)tok * 8 + e]; mx = fmaxf(mx, l[e]); }
    float sum = 0.f;
#pragma unroll
    for (int e = 0; e < 8; ++e) { p[e] = __expf(l[e] - mx); sum += p[e]; }
    float inv = 1.f / sum;
#pragma unroll
    for (int e = 0; e < 8; ++e) p[e] *= inv;
    int i1 = 0;
#pragma unroll
    for (int e = 1; e < 8; ++e) if (p[e] > p[i1]) i1 = e;
    int i2 = -1;
#pragma unroll
    for (int e = 0; e < 8; ++e) {
        if (e == i1) continue;
        if (i2 < 0 || p[e] > p[i2]) i2 = e;
    }
    float tv = p[i1] + p[i2];
    float w1 = p[i1] / tv, w2 = p[i2] / tv;

    const size_t NEC = (size_t)N_TOK * E_EXP * CAPV;
    v4f* dbase = (v4f*)(out + (size_t)tok * E_EXP * CAPV);
    v4f* cbase = (v4f*)(out + NEC + (size_t)tok * E_EXP * CAPV);
    const int NF4 = E_EXP * CAPV / 4;
#pragma unroll
    for (int it = 0; it < NF4 / 256; ++it) {
        int f = it * 256 + tid;
        int e = f / (CAPV / 4);
        int c4 = f - e * (CAPV / 4);
        v4f dv = {0.f, 0.f, 0.f, 0.f};
        v4f cv = {0.f, 0.f, 0.f, 0.f};
        if (c4 == 0) {
            if (e == i1) { dv[0] = 1.f; cv[0] = w1; }
            else if (e == i2) { dv[0] = 1.f; cv[0] = w2; }
        }
        __builtin_nontemporal_store(dv, dbase + f);
        __builtin_nontemporal_store(cv, cbase + f);
    }
    if (tid < 2) {
        float4 pv = tid == 0 ? make_float4(p[0], p[1], p[2], p[3])
                             : make_float4(p[4], p[5], p[6], p[7]);
        ((float4*)(out + 2 * NEC + (size_t)tok * 8))[tid] = pv;
    }
}

// ---------------------------------------------------------------- aux loss
__global__ void aux_k(const float* __restrict__ probs, float* __restrict__ out_aux) {
    __shared__ float part[256];
    int tid = threadIdx.x;
    int e = tid & 7, chunk = tid >> 3;
    float s = 0.f;
    for (int t = chunk * 128; t < (chunk + 1) * 128; ++t)
        s += probs[(size_t)t * 8 + e];
    part[tid] = s;
    __syncthreads();
    if (tid < 8) {
        float tot = 0.f;
        for (int c = 0; c < 32; ++c) tot += part[c * 8 + e];
        part[tid] = tot / (float)N_TOK;
    }
    __syncthreads();
    if (tid == 0) {
        float aux = 0.f;
        for (int e2 = 0; e2 < 8; ++e2) {
            float pm = part[e2];
            aux += pm * logf(pm * 8.f + 1e-9f);
        }
        *out_aux = aux;
    }
}

// ---------------------------------------------------------------- launch
extern "C" void kernel_launch(void* const* d_in, const int* in_sizes, int n_in,
                              void* d_out, int out_size, void* d_ws, size_t ws_size,
                              hipStream_t stream) {
    const float* hid = (const float*)d_in[0];
    const float* pos = (const float*)d_in[1];
    const float* We1 = (const float*)d_in[2];
    const float* be1 = (const float*)d_in[3];
    const float* We2 = (const float*)d_in[4];
    const float* be2 = (const float*)d_in[5];
    const float* Ws1 = (const float*)d_in[6];
    const float* bs1 = (const float*)d_in[7];
    const float* Ws2 = (const float*)d_in[8];
    const float* bs2 = (const float*)d_in[9];
    const float* Wq  = (const float*)d_in[10]; const float* bq = (const float*)d_in[11];
    const float* Wk  = (const float*)d_in[12]; const float* bk = (const float*)d_in[13];
    const float* Wv  = (const float*)d_in[14]; const float* bv = (const float*)d_in[15];
    const float* Wo  = (const float*)d_in[16]; const float* bo = (const float*)d_in[17];
    const float* Wr1 = (const float*)d_in[18]; const float* br1 = (const float*)d_in[19];
    const float* Wr2 = (const float*)d_in[20]; const float* br2 = (const float*)d_in[21];

    float* out = (float*)d_out;
    char* base = (char*)d_ws;
    const size_t AC  = (size_t)N_TOK * H_DIM;
    const size_t SPC = AC * 2;
    const size_t FB  = AC * 4;
    const size_t WSZ = (size_t)1024 * 1024 * 4;

    unsigned short* B1hi = (unsigned short*)(base);
    unsigned short* B1lo = (unsigned short*)(base + SPC);
    unsigned short* B2hi = (unsigned short*)(base + FB);
    unsigned short* B2lo = (unsigned short*)(base + FB + SPC);
    unsigned short* Qhi  = (unsigned short*)(base + 2 * FB);
    unsigned short* Qlo  = (unsigned short*)(base + 2 * FB + SPC);
    unsigned short* Khi  = (unsigned short*)(base + 3 * FB);
    unsigned short* Klo  = (unsigned short*)(base + 3 * FB + SPC);
    unsigned short* VThi = (unsigned short*)(base + 4 * FB);
    unsigned short* VTlo = (unsigned short*)(base + 4 * FB + SPC);
    float* h1f = (float*)(base + 3 * FB);

    char* wbase = base + 5 * FB;
    bool batched = ws_size >= 5 * FB + 7 * WSZ + (1u << 20);
    unsigned short* Whi[7];
    unsigned short* Wlo[7];
    for (int i = 0; i < 7; ++i) {
        size_t off = batched ? (size_t)i * WSZ : 0;
        Whi[i] = (unsigned short*)(wbase + off);
        Wlo[i] = (unsigned short*)(wbase + off + WSZ / 2);
    }
    char* smalls = wbase + (batched ? 7 * WSZ : WSZ);
    float* wr2t    = (float*)smalls;
    float* seas24  = wr2t + 8192;
    float* seasons = seas24 + 6144;
    float* logits  = seasons + 2048;

    const size_t NEC = (size_t)N_TOK * E_EXP * CAPV;
    const float QSCALE = 0.08838834764831845f;

    float* OP = out;
    float* ML = out + (size_t)2 * 16 * 2048 * 128;

    dim3 blk(256);
    dim3 wg(16, 16);

    prep_k<<<4160, 256, 0, stream>>>(hid, B1hi, B1lo, Ws1, bs1, Ws2, bs2,
                                     seasons, seas24, Wr2, wr2t);

    const float* wsrc[7] = {We1, We2, Wq, Wk, Wv, Wo, Wr1};
    if (batched) {
        WBatch wb;
        for (int i = 0; i < 7; ++i) { wb.src[i] = wsrc[i]; wb.dh[i] = Whi[i]; wb.dl[i] = Wlo[i]; }
        wconv_batch_k<<<dim3(16, 16, 7), blk, 0, stream>>>(wb);
    }

    auto conv = [&](int i) {
        if (!batched) wconv_t_k<<<wg, blk, 0, stream>>>(wsrc[i], Whi[i], Wlo[i]);
    };

    conv(0);
    gemm_split<1, 0, 1, 0><<<512, blk, 0, stream>>>(B1hi, B1lo, Whi[0], Wlo[0], be1,
        nullptr, B2hi, B2lo,
        We1 + (size_t)1024 * 1024, We1 + (size_t)1025 * 1024, seasons, nullptr, nullptr, 1.f);
    conv(1);
    gemm_split<2, 0, 1, 0><<<512, blk, 0, stream>>>(B2hi, B2lo, Whi[1], Wlo[1], be2,
        nullptr, B1hi, B1lo, nullptr, nullptr, nullptr, pos, seas24, 1.f);
    conv(2);
    gemm_split<0, 0, 1, 0><<<512, blk, 0, stream>>>(B1hi, B1lo, Whi[2], Wlo[2], bq,
        nullptr, Qhi, Qlo, nullptr, nullptr, nullptr, nullptr, nullptr, QSCALE);
    conv(3);
    gemm_split<0, 0, 1, 0><<<512, blk, 0, stream>>>(B1hi, B1lo, Whi[3], Wlo[3], bk,
        nullptr, Khi, Klo, nullptr, nullptr, nullptr, nullptr, nullptr, 1.f);
    conv(4);
    gemm_split<0, 0, 0, 1><<<512, blk, 0, stream>>>(B1hi, B1lo, Whi[4], Wlo[4], bv,
        nullptr, VThi, VTlo, nullptr, nullptr, nullptr, nullptr, nullptr, 1.f);

    attn_mfma_k<<<1024, 256, 0, stream>>>(Qhi, Qlo, Khi, Klo, VThi, VTlo, OP, ML);
    attn_combine_k<<<2048, 256, 0, stream>>>(OP, ML, B2hi, B2lo);

    conv(5);
    gemm_split<0, 0, 1, 0><<<512, blk, 0, stream>>>(B2hi, B2lo, Whi[5], Wlo[5], bo,
        nullptr, B1hi, B1lo, nullptr, nullptr, nullptr, nullptr, nullptr, 1.f);
    conv(6);
    gemm_split<3, 1, 0, 0><<<512, blk, 0, stream>>>(B1hi, B1lo, Whi[6], Wlo[6], br1,
        h1f, nullptr, nullptr, nullptr, nullptr, nullptr, nullptr, nullptr, 1.f);

    logits_k<<<512, 256, 0, stream>>>(h1f, wr2t, br2, logits);
    topk_fill_k<<<4096, 256, 0, stream>>>(logits, out);
    aux_k<<<1, 256, 0, stream>>>(out + 2 * NEC, out + 2 * NEC + (size_t)N_TOK * E_EXP);
}

// Round 11
// 599.327 us; speedup vs baseline: 1.1345x; 1.0192x over previous
//
#include <hip/hip_runtime.h>
#include <hip/hip_fp16.h>
#include <math.h>

#define N_TOK 4096
#define S_LEN 2048
#define H_DIM 1024
#define E_EXP 8
#define CAPV  1536
#define NHEAD 8
#define HDHD  128

typedef __attribute__((ext_vector_type(8))) _Float16 v8h;
typedef __attribute__((ext_vector_type(4))) float v4f;

__device__ __forceinline__ void splitf16(float v, unsigned short& h, unsigned short& l) {
    __half hh = __float2half(v);
    h = __half_as_ushort(hh);
    l = __half_as_ushort(__float2half(v - __half2float(hh)));
}

__device__ __forceinline__ void gld_lds16(const void* g, void* l) {
    __builtin_amdgcn_global_load_lds(
        (const __attribute__((address_space(1))) unsigned int*)g,
        (__attribute__((address_space(3))) unsigned int*)l,
        16, 0, 0);
}

// ---------------------------------------------------------------- fused prep
__global__ __launch_bounds__(256) void prep_k(
    const float* __restrict__ hid, unsigned short* __restrict__ hi,
    unsigned short* __restrict__ lo,
    const float* __restrict__ Ws1, const float* __restrict__ bs1,
    const float* __restrict__ Ws2, const float* __restrict__ bs2,
    float* __restrict__ seasons, float* __restrict__ seas24,
    const float* __restrict__ Wr2, float* __restrict__ wr2t) {
    __shared__ float hbuf[256];
    int blk = blockIdx.x;
    int tid = threadIdx.x;
    if (blk < 4096) {
        int i = blk * 256 + tid;
        float4 v = ((const float4*)hid)[i];
        ushort4 h, l;
        splitf16(v.x, h.x, l.x);
        splitf16(v.y, h.y, l.y);
        splitf16(v.z, h.z, l.z);
        splitf16(v.w, h.w, l.w);
        ((ushort4*)hi)[i] = h;
        ((ushort4*)lo)[i] = l;
    } else if (blk < 4104) {
        int s = (blk - 4096) * 256 + tid;
        if (s < S_LEN) {
            double a = (double)s * 2.0 * M_PI / 24.0;
            seasons[s] = (float)sin(a);
        }
    } else if (blk < 4128) {
        int m = blk - 4104;
        double a = (double)m * 2.0 * M_PI / 24.0;
        float sv = (float)sin(a);
        int j = tid;
        hbuf[j] = fmaxf(sv * Ws1[j] + bs1[j], 0.f);
        __syncthreads();
        float acc = bs2[j];
        for (int i = 0; i < 256; ++i) acc = fmaf(hbuf[i], Ws2[i * 256 + j], acc);
        seas24[m * 256 + j] = acc;
    } else {
        int i = (blk - 4128) * 256 + tid;
        int k = i >> 3, e = i & 7;
        wr2t[e * 1024 + k] = Wr2[i];
    }
}

// ---------------------------------------------------------------- W[1024][1024] -> W^T hi/lo f16
__device__ __forceinline__ void wconv_body(const float* __restrict__ W,
                                           unsigned short* __restrict__ Thi,
                                           unsigned short* __restrict__ Tlo) {
    __shared__ unsigned short Hs[64][65];
    __shared__ unsigned short Ls[64][65];
    int k0 = blockIdx.y * 64, n0 = blockIdx.x * 64;
    int tid = threadIdx.x;
#pragma unroll
    for (int i = 0; i < 4; ++i) {
        int idx = tid + i * 256;
        int kk = idx >> 4, n4 = idx & 15;
        float4 v = *(const float4*)(W + (size_t)(k0 + kk) * 1024 + n0 + n4 * 4);
        unsigned short h, l;
        splitf16(v.x, h, l); Hs[n4 * 4 + 0][kk] = h; Ls[n4 * 4 + 0][kk] = l;
        splitf16(v.y, h, l); Hs[n4 * 4 + 1][kk] = h; Ls[n4 * 4 + 1][kk] = l;
        splitf16(v.z, h, l); Hs[n4 * 4 + 2][kk] = h; Ls[n4 * 4 + 2][kk] = l;
        splitf16(v.w, h, l); Hs[n4 * 4 + 3][kk] = h; Ls[n4 * 4 + 3][kk] = l;
    }
    __syncthreads();
#pragma unroll
    for (int i = 0; i < 4; ++i) {
        int idx = tid + i * 256;
        int n = idx >> 4, k4 = idx & 15;
        ushort4 h = make_ushort4(Hs[n][k4 * 4], Hs[n][k4 * 4 + 1], Hs[n][k4 * 4 + 2], Hs[n][k4 * 4 + 3]);
        ushort4 l = make_ushort4(Ls[n][k4 * 4], Ls[n][k4 * 4 + 1], Ls[n][k4 * 4 + 2], Ls[n][k4 * 4 + 3]);
        *(ushort4*)(Thi + (size_t)(n0 + n) * 1024 + k0 + k4 * 4) = h;
        *(ushort4*)(Tlo + (size_t)(n0 + n) * 1024 + k0 + k4 * 4) = l;
    }
}

struct WBatch {
    const float* src[7];
    unsigned short* dh[7];
    unsigned short* dl[7];
};

__global__ __launch_bounds__(256) void wconv_batch_k(WBatch wb) {
    int i = blockIdx.z;
    wconv_body(wb.src[i], wb.dh[i], wb.dl[i]);
}

// ---------------------------------------------------------------- split-f16 MFMA GEMM (dbuf + XCD swizzle)
template <int MODE, int EMITF, int EMITS, int EMITT>
__global__ __launch_bounds__(256, 2) void gemm_split(
    const unsigned short* __restrict__ Ahi, const unsigned short* __restrict__ Alo,
    const unsigned short* __restrict__ WThi, const unsigned short* __restrict__ WTlo,
    const float* __restrict__ bias, float* __restrict__ Cf,
    unsigned short* __restrict__ Chi, unsigned short* __restrict__ Clo,
    const float* __restrict__ rowT, const float* __restrict__ rowS,
    const float* __restrict__ seasons, const float* __restrict__ pos,
    const float* __restrict__ seas24, float escale) {
    __shared__ unsigned short Ash[2][128 * 32];
    __shared__ unsigned short Asl[2][128 * 32];
    __shared__ unsigned short Bsh[2][64 * 32];
    __shared__ unsigned short Bsl[2][64 * 32];
    int tid = threadIdx.x;
    int lane = tid & 63, w = tid >> 6;
    int l15 = lane & 15, l16 = lane >> 4;
    int wm = (w >> 1) * 64, wn = (w & 1) * 32;

    int bid = blockIdx.x;
    int mp = (bid & 7) + ((bid >> 7) << 3);
    int np = (bid >> 3) & 15;
    int m0 = mp * 128, n0 = np * 64;

    int ac0 = w * 128 + lane;
    int ac1 = ac0 + 64;
    int bc  = w * 64 + lane;
    int ar0 = ac0 >> 2, ar1 = ac1 >> 2, bn = bc >> 2;
    size_t a_src0 = (size_t)(m0 + ar0) * 1024 + (((ac0 & 3) ^ (ar0 & 3)) * 8);
    size_t a_src1 = (size_t)(m0 + ar1) * 1024 + (((ac1 & 3) ^ (ar1 & 3)) * 8);
    size_t b_src  = (size_t)(n0 + bn) * 1024 + (((bc & 3) ^ (bn & 3)) * 8);

    int a_off[4], b_off[2];
#pragma unroll
    for (int mi = 0; mi < 4; ++mi) {
        int row = wm + mi * 16 + l15;
        a_off[mi] = row * 32 + ((l16 ^ (row & 3)) * 8);
    }
#pragma unroll
    for (int ni = 0; ni < 2; ++ni) {
        int n = wn + ni * 16 + l15;
        b_off[ni] = n * 32 + ((l16 ^ (n & 3)) * 8);
    }

    auto STAGE = [&](int buf, int k0) {
        gld_lds16(Ahi + a_src0 + k0, &Ash[buf][ac0 * 8]);
        gld_lds16(Ahi + a_src1 + k0, &Ash[buf][ac1 * 8]);
        gld_lds16(Alo + a_src0 + k0, &Asl[buf][ac0 * 8]);
        gld_lds16(Alo + a_src1 + k0, &Asl[buf][ac1 * 8]);
        gld_lds16(WThi + b_src + k0, &Bsh[buf][bc * 8]);
        gld_lds16(WTlo + b_src + k0, &Bsl[buf][bc * 8]);
    };

    v4f acc[4][2] = {};
    STAGE(0, 0);
    __syncthreads();

    for (int kk = 0; kk < 32; ++kk) {
        int cur = kk & 1;
        if (kk < 31) STAGE(cur ^ 1, (kk + 1) * 32);
        v8h ah[4], al[4], bh[2], bl[2];
#pragma unroll
        for (int mi = 0; mi < 4; ++mi) {
            ah[mi] = *(const v8h*)&Ash[cur][a_off[mi]];
            al[mi] = *(const v8h*)&Asl[cur][a_off[mi]];
        }
#pragma unroll
        for (int ni = 0; ni < 2; ++ni) {
            bh[ni] = *(const v8h*)&Bsh[cur][b_off[ni]];
            bl[ni] = *(const v8h*)&Bsl[cur][b_off[ni]];
        }
#pragma unroll
        for (int mi = 0; mi < 4; ++mi)
#pragma unroll
            for (int ni = 0; ni < 2; ++ni) {
                acc[mi][ni] = __builtin_amdgcn_mfma_f32_16x16x32_f16(ah[mi], bh[ni], acc[mi][ni], 0, 0, 0);
                acc[mi][ni] = __builtin_amdgcn_mfma_f32_16x16x32_f16(al[mi], bh[ni], acc[mi][ni], 0, 0, 0);
                acc[mi][ni] = __builtin_amdgcn_mfma_f32_16x16x32_f16(ah[mi], bl[ni], acc[mi][ni], 0, 0, 0);
            }
        __syncthreads();
    }

    if (EMITT) {
#pragma unroll
        for (int mi = 0; mi < 4; ++mi) {
            int row0 = m0 + wm + mi * 16 + l16 * 4;
            int bb = row0 >> 11, ss = row0 & 2047;
#pragma unroll
            for (int ni = 0; ni < 2; ++ni) {
                int col = n0 + wn + ni * 16 + l15;
                int hh = col >> 7, dd = col & 127;
                size_t base = ((size_t)((bb * 8 + hh) * 128 + dd)) * 2048 + ss;
                ushort4 vh, vl;
                float v0 = acc[mi][ni][0] + bias[col];
                float v1 = acc[mi][ni][1] + bias[col];
                float v2 = acc[mi][ni][2] + bias[col];
                float v3 = acc[mi][ni][3] + bias[col];
                splitf16(v0, vh.x, vl.x);
                splitf16(v1, vh.y, vl.y);
                splitf16(v2, vh.z, vl.z);
                splitf16(v3, vh.w, vl.w);
                *(ushort4*)(Chi + base) = vh;
                *(ushort4*)(Clo + base) = vl;
            }
        }
    } else {
#pragma unroll
        for (int mi = 0; mi < 4; ++mi) {
#pragma unroll
            for (int r = 0; r < 4; ++r) {
                int row = m0 + wm + mi * 16 + l16 * 4 + r;
                int s = row & (S_LEN - 1);
                float tval = 0.f, seval = 0.f;
                if (MODE == 1) { tval = (float)s; seval = seasons[s]; }
#pragma unroll
                for (int ni = 0; ni < 2; ++ni) {
                    int col = n0 + wn + ni * 16 + l15;
                    float v = acc[mi][ni][r] + bias[col];
                    if (MODE == 1) v += tval * rowT[col] + seval * rowS[col];
                    if (MODE == 2) v += pos[(size_t)s * 1024 + col] + seas24[(s % 24) * 256 + (col & 255)];
                    if (MODE == 1 || MODE == 3) v = fmaxf(v, 0.f);
                    size_t o = (size_t)row * 1024 + col;
                    if (EMITF) Cf[o] = v;
                    if (EMITS) {
                        unsigned short hu, lu;
                        splitf16(v * escale, hu, lu);
                        Chi[o] = hu; Clo[o] = lu;
                    }
                }
            }
        }
    }
}

// ---------------------------------------------------------------- fused QKV GEMM
// grid 1536; packed WT3 [3072][1024]: rows 0-1023 Wq^T, 1024-2047 Wk^T, 2048-3071 Wv^T.
// n-blocks 0-15 -> Q (EMITS, scaled), 16-31 -> K (EMITS), 32-47 -> V (EMITT).
// bid = (m%8) + 8*(n + 48*(m/8)) keeps one A-panel's 48 blocks on one XCD.
__global__ __launch_bounds__(256, 2) void gemm_qkv(
    const unsigned short* __restrict__ Ahi, const unsigned short* __restrict__ Alo,
    const unsigned short* __restrict__ WT3hi, const unsigned short* __restrict__ WT3lo,
    const float* __restrict__ bq, const float* __restrict__ bk,
    const float* __restrict__ bv,
    unsigned short* __restrict__ Qhi, unsigned short* __restrict__ Qlo,
    unsigned short* __restrict__ Khi, unsigned short* __restrict__ Klo,
    unsigned short* __restrict__ VThi, unsigned short* __restrict__ VTlo,
    float qscale) {
    __shared__ unsigned short Ash[2][128 * 32];
    __shared__ unsigned short Asl[2][128 * 32];
    __shared__ unsigned short Bsh[2][64 * 32];
    __shared__ unsigned short Bsl[2][64 * 32];
    int tid = threadIdx.x;
    int lane = tid & 63, w = tid >> 6;
    int l15 = lane & 15, l16 = lane >> 4;
    int wm = (w >> 1) * 64, wn = (w & 1) * 32;

    int bid = blockIdx.x;
    int t = bid >> 3;                       // 0..191
    int mp = (bid & 7) + (t / 48) * 8;      // 0..31
    int np = t % 48;                        // 0..47
    int m0 = mp * 128;
    int wn0 = np * 64;                      // packed weight row base

    int ac0 = w * 128 + lane;
    int ac1 = ac0 + 64;
    int bc  = w * 64 + lane;
    int ar0 = ac0 >> 2, ar1 = ac1 >> 2, bn = bc >> 2;
    size_t a_src0 = (size_t)(m0 + ar0) * 1024 + (((ac0 & 3) ^ (ar0 & 3)) * 8);
    size_t a_src1 = (size_t)(m0 + ar1) * 1024 + (((ac1 & 3) ^ (ar1 & 3)) * 8);
    size_t b_src  = (size_t)(wn0 + bn) * 1024 + (((bc & 3) ^ (bn & 3)) * 8);

    int a_off[4], b_off[2];
#pragma unroll
    for (int mi = 0; mi < 4; ++mi) {
        int row = wm + mi * 16 + l15;
        a_off[mi] = row * 32 + ((l16 ^ (row & 3)) * 8);
    }
#pragma unroll
    for (int ni = 0; ni < 2; ++ni) {
        int n = wn + ni * 16 + l15;
        b_off[ni] = n * 32 + ((l16 ^ (n & 3)) * 8);
    }

    auto STAGE = [&](int buf, int k0) {
        gld_lds16(Ahi + a_src0 + k0, &Ash[buf][ac0 * 8]);
        gld_lds16(Ahi + a_src1 + k0, &Ash[buf][ac1 * 8]);
        gld_lds16(Alo + a_src0 + k0, &Asl[buf][ac0 * 8]);
        gld_lds16(Alo + a_src1 + k0, &Asl[buf][ac1 * 8]);
        gld_lds16(WT3hi + b_src + k0, &Bsh[buf][bc * 8]);
        gld_lds16(WT3lo + b_src + k0, &Bsl[buf][bc * 8]);
    };

    v4f acc[4][2] = {};
    STAGE(0, 0);
    __syncthreads();

    for (int kk = 0; kk < 32; ++kk) {
        int cur = kk & 1;
        if (kk < 31) STAGE(cur ^ 1, (kk + 1) * 32);
        v8h ah[4], al[4], bh[2], bl[2];
#pragma unroll
        for (int mi = 0; mi < 4; ++mi) {
            ah[mi] = *(const v8h*)&Ash[cur][a_off[mi]];
            al[mi] = *(const v8h*)&Asl[cur][a_off[mi]];
        }
#pragma unroll
        for (int ni = 0; ni < 2; ++ni) {
            bh[ni] = *(const v8h*)&Bsh[cur][b_off[ni]];
            bl[ni] = *(const v8h*)&Bsl[cur][b_off[ni]];
        }
#pragma unroll
        for (int mi = 0; mi < 4; ++mi)
#pragma unroll
            for (int ni = 0; ni < 2; ++ni) {
                acc[mi][ni] = __builtin_amdgcn_mfma_f32_16x16x32_f16(ah[mi], bh[ni], acc[mi][ni], 0, 0, 0);
                acc[mi][ni] = __builtin_amdgcn_mfma_f32_16x16x32_f16(al[mi], bh[ni], acc[mi][ni], 0, 0, 0);
                acc[mi][ni] = __builtin_amdgcn_mfma_f32_16x16x32_f16(ah[mi], bl[ni], acc[mi][ni], 0, 0, 0);
            }
        __syncthreads();
    }

    if (np >= 32) {
        // V -> transposed split emit
        const float* bias = bv;
        int n0 = (np - 32) * 64;
#pragma unroll
        for (int mi = 0; mi < 4; ++mi) {
            int row0 = m0 + wm + mi * 16 + l16 * 4;
            int bb = row0 >> 11, ss = row0 & 2047;
#pragma unroll
            for (int ni = 0; ni < 2; ++ni) {
                int col = n0 + wn + ni * 16 + l15;
                int hh = col >> 7, dd = col & 127;
                size_t base = ((size_t)((bb * 8 + hh) * 128 + dd)) * 2048 + ss;
                ushort4 vh, vl;
                float v0 = acc[mi][ni][0] + bias[col];
                float v1 = acc[mi][ni][1] + bias[col];
                float v2 = acc[mi][ni][2] + bias[col];
                float v3 = acc[mi][ni][3] + bias[col];
                splitf16(v0, vh.x, vl.x);
                splitf16(v1, vh.y, vl.y);
                splitf16(v2, vh.z, vl.z);
                splitf16(v3, vh.w, vl.w);
                *(ushort4*)(VThi + base) = vh;
                *(ushort4*)(VTlo + base) = vl;
            }
        }
    } else {
        const float* bias = np < 16 ? bq : bk;
        unsigned short* Dhi = np < 16 ? Qhi : Khi;
        unsigned short* Dlo = np < 16 ? Qlo : Klo;
        float esc = np < 16 ? qscale : 1.f;
        int n0 = (np & 15) * 64;
#pragma unroll
        for (int mi = 0; mi < 4; ++mi) {
#pragma unroll
            for (int r = 0; r < 4; ++r) {
                int row = m0 + wm + mi * 16 + l16 * 4 + r;
#pragma unroll
                for (int ni = 0; ni < 2; ++ni) {
                    int col = n0 + wn + ni * 16 + l15;
                    float v = (acc[mi][ni][r] + bias[col]) * esc;
                    size_t o = (size_t)row * 1024 + col;
                    unsigned short hu, lu;
                    splitf16(v, hu, lu);
                    Dhi[o] = hu; Dlo[o] = lu;
                }
            }
        }
    }
}

// ---------------------------------------------------------------- MFMA attention v4 + XCD swizzle
__global__ __launch_bounds__(256, 4) void attn_mfma_k(
    const unsigned short* __restrict__ qhi, const unsigned short* __restrict__ qlo,
    const unsigned short* __restrict__ khi, const unsigned short* __restrict__ klo,
    const unsigned short* __restrict__ vthi, const unsigned short* __restrict__ vtlo,
    float* __restrict__ OP, float* __restrict__ ML) {
    __shared__ unsigned short Ks_hi[32 * 128];
    __shared__ unsigned short Ks_lo[32 * 128];
    __shared__ unsigned short Vs_hi[128 * 32];
    __shared__ unsigned short Vs_lo[128 * 32];
    __shared__ unsigned int   Ps[64 * 32];

    int p = blockIdx.x;
    int x = (p >> 3) & 31;
    int g = (p & 7) + ((p >> 8) << 3);
    int bh = g >> 1, z = g & 1;
    int b = bh >> 3, h = bh & 7;
    int q0 = x * 64;
    int tid = threadIdx.x;
    int lane = tid & 63, w = tid >> 6;
    int l15 = lane & 15, l16 = lane >> 4;
    int wm = w * 16;

    v8h qa_h[4], qa_l[4];
    {
        size_t qrow = (size_t)(b * S_LEN + q0 + wm + l15) * H_DIM + h * HDHD;
#pragma unroll
        for (int ks = 0; ks < 4; ++ks) {
            qa_h[ks] = *(const v8h*)(qhi + qrow + ks * 32 + l16 * 8);
            qa_l[ks] = *(const v8h*)(qlo + qrow + ks * 32 + l16 * 8);
        }
    }

    int ktok1 = tid >> 4, kslot1 = tid & 15;
    int ktok2 = ktok1 + 16;
    size_t ksrc1 = (size_t)(b * S_LEN + ktok1) * H_DIM + h * HDHD + ((kslot1 ^ (ktok1 & 7)) * 8);
    size_t ksrc2 = (size_t)(b * S_LEN + ktok2) * H_DIM + h * HDHD + ((kslot1 ^ (ktok2 & 7)) * 8);
    int vd1 = tid >> 2, vslot1 = tid & 3;
    int vd2 = vd1 + 64;
    size_t vsrc1 = (size_t)(bh * HDHD + vd1) * S_LEN + ((vslot1 ^ ((vd1 >> 1) & 3)) * 8);
    size_t vsrc2 = (size_t)(bh * HDHD + vd2) * S_LEN + ((vslot1 ^ ((vd2 >> 1) & 3)) * 8);

    v4f accO[8] = {};
    float mreg[4] = {-1e30f, -1e30f, -1e30f, -1e30f};
    float lreg[4] = {};

    int kt0 = z * 1024;
    for (int it = 0; it < 32; ++it) {
        int kt = kt0 + it * 32;
        __syncthreads();
        size_t koff = (size_t)kt * H_DIM;
        gld_lds16(khi + ksrc1 + koff, &Ks_hi[tid * 8]);
        gld_lds16(khi + ksrc2 + koff, &Ks_hi[(tid + 256) * 8]);
        gld_lds16(klo + ksrc1 + koff, &Ks_lo[tid * 8]);
        gld_lds16(klo + ksrc2 + koff, &Ks_lo[(tid + 256) * 8]);
        gld_lds16(vthi + vsrc1 + kt, &Vs_hi[tid * 8]);
        gld_lds16(vthi + vsrc2 + kt, &Vs_hi[(tid + 256) * 8]);
        gld_lds16(vtlo + vsrc1 + kt, &Vs_lo[tid * 8]);
        gld_lds16(vtlo + vsrc2 + kt, &Vs_lo[(tid + 256) * 8]);
        __syncthreads();

        v4f s0 = {}, s1 = {};
#pragma unroll
        for (int ks = 0; ks < 4; ++ks) {
#pragma unroll
            for (int nt = 0; nt < 2; ++nt) {
                int tok = nt * 16 + l15;
                int slot = (ks * 4 + l16) ^ (tok & 7);
                v8h bhf = *(const v8h*)&Ks_hi[tok * 128 + slot * 8];
                v8h blf = *(const v8h*)&Ks_lo[tok * 128 + slot * 8];
                v4f& ss = nt ? s1 : s0;
                ss = __builtin_amdgcn_mfma_f32_16x16x32_f16(qa_h[ks], bhf, ss, 0, 0, 0);
                ss = __builtin_amdgcn_mfma_f32_16x16x32_f16(qa_l[ks], bhf, ss, 0, 0, 0);
                ss = __builtin_amdgcn_mfma_f32_16x16x32_f16(qa_h[ks], blf, ss, 0, 0, 0);
            }
        }

        float p0[4], p1[4], alpha[4];
#pragma unroll
        for (int r = 0; r < 4; ++r) {
            float tmax = fmaxf(s0[r], s1[r]);
            tmax = fmaxf(tmax, __shfl_xor(tmax, 1));
            tmax = fmaxf(tmax, __shfl_xor(tmax, 2));
            tmax = fmaxf(tmax, __shfl_xor(tmax, 4));
            tmax = fmaxf(tmax, __shfl_xor(tmax, 8));
            float mnew = fmaxf(mreg[r], tmax);
            alpha[r] = __expf(mreg[r] - mnew);
            p0[r] = __expf(s0[r] - mnew);
            p1[r] = __expf(s1[r] - mnew);
            float lt = p0[r] + p1[r];
            lt += __shfl_xor(lt, 1);
            lt += __shfl_xor(lt, 2);
            lt += __shfl_xor(lt, 4);
            lt += __shfl_xor(lt, 8);
            lreg[r] = lreg[r] * alpha[r] + lt;
            mreg[r] = mnew;
        }
#pragma unroll
        for (int nt = 0; nt < 8; ++nt)
#pragma unroll
            for (int r = 0; r < 4; ++r) accO[nt][r] *= alpha[r];

#pragma unroll
        for (int r = 0; r < 4; ++r) {
            int qq = wm + l16 * 4 + r;
            unsigned short ph, pl;
            splitf16(p0[r], ph, pl);
            int k0i = l15;
            Ps[qq * 32 + ((((k0i >> 2) ^ (qq & 7)) << 2) | (k0i & 3))] =
                (unsigned)ph | ((unsigned)pl << 16);
            splitf16(p1[r], ph, pl);
            int k1i = 16 + l15;
            Ps[qq * 32 + ((((k1i >> 2) ^ (qq & 7)) << 2) | (k1i & 3))] =
                (unsigned)ph | ((unsigned)pl << 16);
        }

        int qq = wm + l15;
        int sA = (l16 * 2) ^ (qq & 7);
        int sB = (l16 * 2 + 1) ^ (qq & 7);
        uint4 ua = *(const uint4*)&Ps[qq * 32 + sA * 4];
        uint4 ub = *(const uint4*)&Ps[qq * 32 + sB * 4];
        uint4 ahw, alw;
        ahw.x = (ua.x & 0xffffu) | (ua.y << 16);
        ahw.y = (ua.z & 0xffffu) | (ua.w << 16);
        ahw.z = (ub.x & 0xffffu) | (ub.y << 16);
        ahw.w = (ub.z & 0xffffu) | (ub.w << 16);
        alw.x = (ua.x >> 16) | (ua.y & 0xffff0000u);
        alw.y = (ua.z >> 16) | (ua.w & 0xffff0000u);
        alw.z = (ub.x >> 16) | (ub.y & 0xffff0000u);
        alw.w = (ub.z >> 16) | (ub.w & 0xffff0000u);
        v8h pA_h = __builtin_bit_cast(v8h, ahw);
        v8h pA_l = __builtin_bit_cast(v8h, alw);
#pragma unroll
        for (int nt = 0; nt < 8; ++nt) {
            int d = nt * 16 + l15;
            int slot = l16 ^ ((d >> 1) & 3);
            v8h vhf = *(const v8h*)&Vs_hi[d * 32 + slot * 8];
            v8h vlf = *(const v8h*)&Vs_lo[d * 32 + slot * 8];
            accO[nt] = __builtin_amdgcn_mfma_f32_16x16x32_f16(pA_h, vhf, accO[nt], 0, 0, 0);
            accO[nt] = __builtin_amdgcn_mfma_f32_16x16x32_f16(pA_l, vhf, accO[nt], 0, 0, 0);
            accO[nt] = __builtin_amdgcn_mfma_f32_16x16x32_f16(pA_h, vlf, accO[nt], 0, 0, 0);
        }
    }

#pragma unroll
    for (int r = 0; r < 4; ++r) {
        if (l15 == 0) {
            int q = q0 + wm + l16 * 4 + r;
            size_t mlo = ((size_t)(z * 16 + bh) * 2048 + q) * 2;
            ML[mlo] = mreg[r];
            ML[mlo + 1] = lreg[r];
        }
    }
#pragma unroll
    for (int nt = 0; nt < 8; ++nt) {
#pragma unroll
        for (int r = 0; r < 4; ++r) {
            int q = q0 + wm + l16 * 4 + r;
            size_t o = ((size_t)(z * 16 + bh) * 2048 + q) * 128 + nt * 16 + l15;
            OP[o] = accO[nt][r];
        }
    }
}

// ---------------------------------------------------------------- flash combine
__global__ __launch_bounds__(256) void attn_combine_k(
    const float* __restrict__ OP, const float* __restrict__ ML,
    unsigned short* __restrict__ ctx_hi, unsigned short* __restrict__ ctx_lo) {
    int tid = threadIdx.x;
    int R = blockIdx.x * 16 + (tid >> 4);
    int bh = R >> 11, q = R & 2047;
    int b = bh >> 3, h = bh & 7;
    int d0 = (tid & 15) * 8;
    size_t ml0 = ((size_t)bh * 2048 + q) * 2;
    size_t ml1 = ((size_t)(16 + bh) * 2048 + q) * 2;
    float m0 = ML[ml0], l0 = ML[ml0 + 1];
    float m1 = ML[ml1], l1 = ML[ml1 + 1];
    float m = fmaxf(m0, m1);
    float w0 = __expf(m0 - m), w1 = __expf(m1 - m);
    float inv = 1.f / (w0 * l0 + w1 * l1);
    const float* O0 = OP + ((size_t)bh * 2048 + q) * 128 + d0;
    const float* O1 = OP + ((size_t)(16 + bh) * 2048 + q) * 128 + d0;
    size_t dst = ((size_t)(b * 2048 + q)) * 1024 + h * 128 + d0;
    float4 a0 = *(const float4*)O0;
    float4 a1 = *(const float4*)(O0 + 4);
    float4 c0 = *(const float4*)O1;
    float4 c1 = *(const float4*)(O1 + 4);
    ushort4 h0, h1, lo0, lo1;
    splitf16((w0 * a0.x + w1 * c0.x) * inv, h0.x, lo0.x);
    splitf16((w0 * a0.y + w1 * c0.y) * inv, h0.y, lo0.y);
    splitf16((w0 * a0.z + w1 * c0.z) * inv, h0.z, lo0.z);
    splitf16((w0 * a0.w + w1 * c0.w) * inv, h0.w, lo0.w);
    splitf16((w0 * a1.x + w1 * c1.x) * inv, h1.x, lo1.x);
    splitf16((w0 * a1.y + w1 * c1.y) * inv, h1.y, lo1.y);
    splitf16((w0 * a1.z + w1 * c1.z) * inv, h1.z, lo1.z);
    splitf16((w0 * a1.w + w1 * c1.w) * inv, h1.w, lo1.w);
    *(ushort4*)(ctx_hi + dst) = h0;
    *(ushort4*)(ctx_hi + dst + 4) = h1;
    *(ushort4*)(ctx_lo + dst) = lo0;
    *(ushort4*)(ctx_lo + dst + 4) = lo1;
}

// ---------------------------------------------------------------- streaming zero-fill (max write BW)
__global__ __launch_bounds__(256) void fill_k(float* __restrict__ out) {
    size_t idx = (size_t)blockIdx.x * 256 + threadIdx.x;
    const size_t stride = (size_t)2048 * 256;
    v4f z = {0.f, 0.f, 0.f, 0.f};
    v4f* o = (v4f*)out;
#pragma unroll
    for (int i = 0; i < 48; ++i)
        __builtin_nontemporal_store(z, o + idx + (size_t)i * stride);
}

// ---------------------------------------------------------------- router logits
__global__ __launch_bounds__(256) void logits_k(const float* __restrict__ h1,
                                                const float* __restrict__ Wr2T,
                                                const float* __restrict__ br2,
                                                float* __restrict__ logits) {
    __shared__ float part[256];
    int tid = threadIdx.x;
    int tok8 = tid >> 5;
    int e = (tid >> 2) & 7;
    int ch = tid & 3;
    int tok = blockIdx.x * 8 + tok8;
    const float4* h4 = (const float4*)(h1 + (size_t)tok * 1024 + ch * 256);
    const float4* w4 = (const float4*)(Wr2T + (size_t)e * 1024 + ch * 256);
    float acc = 0.f;
#pragma unroll
    for (int i = 0; i < 64; ++i) {
        float4 a = h4[i];
        float4 bb = w4[i];
        acc = fmaf(a.x, bb.x, fmaf(a.y, bb.y, fmaf(a.z, bb.z, fmaf(a.w, bb.w, acc))));
    }
    part[tid] = acc;
    __syncthreads();
    if (ch == 0) {
        float s = part[tid] + part[tid + 1] + part[tid + 2] + part[tid + 3] + br2[e];
        logits[(size_t)tok * 8 + e] = s;
    }
}

// ---------------------------------------------------------------- softmax + top2 scatter (after fill)
__global__ __launch_bounds__(256) void topk_scatter_k(const float* __restrict__ logits,
                                                      float* __restrict__ out) {
    int tok = blockIdx.x * 256 + threadIdx.x;
    if (tok >= N_TOK) return;
    float l[8], p[8];
    float mx = -1e30f;
#pragma unroll
    for (int e = 0; e < 8; ++e) { l[e] = logits[(size_t)tok * 8 + e]; mx = fmaxf(mx, l[e]); }
    float sum = 0.f;
#pragma unroll
    for (int e = 0; e < 8; ++e) { p[e] = __expf(l[e] - mx); sum += p[e]; }
    float inv = 1.f / sum;
#pragma unroll
    for (int e = 0; e < 8; ++e) p[e] *= inv;
    const size_t NEC = (size_t)N_TOK * E_EXP * CAPV;
    float* probs_out = out + 2 * NEC;
#pragma unroll
    for (int e = 0; e < 8; ++e) probs_out[(size_t)tok * 8 + e] = p[e];
    int i1 = 0;
#pragma unroll
    for (int e = 1; e < 8; ++e) if (p[e] > p[i1]) i1 = e;
    int i2 = -1;
#pragma unroll
    for (int e = 0; e < 8; ++e) {
        if (e == i1) continue;
        if (i2 < 0 || p[e] > p[i2]) i2 = e;
    }
    float v1 = p[i1], v2 = p[i2], tv = v1 + v2;
    size_t base = (size_t)tok * E_EXP * CAPV;
    out[base + (size_t)i1 * CAPV] = 1.f;
    out[base + (size_t)i2 * CAPV] = 1.f;
    out[NEC + base + (size_t)i1 * CAPV] = v1 / tv;
    out[NEC + base + (size_t)i2 * CAPV] = v2 / tv;
}

// ---------------------------------------------------------------- aux loss
__global__ void aux_k(const float* __restrict__ probs, float* __restrict__ out_aux) {
    __shared__ float part[256];
    int tid = threadIdx.x;
    int e = tid & 7, chunk = tid >> 3;
    float s = 0.f;
    for (int t = chunk * 128; t < (chunk + 1) * 128; ++t)
        s += probs[(size_t)t * 8 + e];
    part[tid] = s;
    __syncthreads();
    if (tid < 8) {
        float tot = 0.f;
        for (int c = 0; c < 32; ++c) tot += part[c * 8 + e];
        part[tid] = tot / (float)N_TOK;
    }
    __syncthreads();
    if (tid == 0) {
        float aux = 0.f;
        for (int e2 = 0; e2 < 8; ++e2) {
            float pm = part[e2];
            aux += pm * logf(pm * 8.f + 1e-9f);
        }
        *out_aux = aux;
    }
}

// ---------------------------------------------------------------- launch
extern "C" void kernel_launch(void* const* d_in, const int* in_sizes, int n_in,
                              void* d_out, int out_size, void* d_ws, size_t ws_size,
                              hipStream_t stream) {
    const float* hid = (const float*)d_in[0];
    const float* pos = (const float*)d_in[1];
    const float* We1 = (const float*)d_in[2];
    const float* be1 = (const float*)d_in[3];
    const float* We2 = (const float*)d_in[4];
    const float* be2 = (const float*)d_in[5];
    const float* Ws1 = (const float*)d_in[6];
    const float* bs1 = (const float*)d_in[7];
    const float* Ws2 = (const float*)d_in[8];
    const float* bs2 = (const float*)d_in[9];
    const float* Wq  = (const float*)d_in[10]; const float* bq = (const float*)d_in[11];
    const float* Wk  = (const float*)d_in[12]; const float* bk = (const float*)d_in[13];
    const float* Wv  = (const float*)d_in[14]; const float* bv = (const float*)d_in[15];
    const float* Wo  = (const float*)d_in[16]; const float* bo = (const float*)d_in[17];
    const float* Wr1 = (const float*)d_in[18]; const float* br1 = (const float*)d_in[19];
    const float* Wr2 = (const float*)d_in[20]; const float* br2 = (const float*)d_in[21];

    float* out = (float*)d_out;
    char* base = (char*)d_ws;
    const size_t AC  = (size_t)N_TOK * H_DIM;
    const size_t SPC = AC * 2;
    const size_t FB  = AC * 4;
    const size_t MB  = (size_t)1 << 20;

    unsigned short* B1hi = (unsigned short*)(base);
    unsigned short* B1lo = (unsigned short*)(base + SPC);
    unsigned short* B2hi = (unsigned short*)(base + FB);
    unsigned short* B2lo = (unsigned short*)(base + FB + SPC);
    unsigned short* Qhi  = (unsigned short*)(base + 2 * FB);
    unsigned short* Qlo  = (unsigned short*)(base + 2 * FB + SPC);
    unsigned short* Khi  = (unsigned short*)(base + 3 * FB);
    unsigned short* Klo  = (unsigned short*)(base + 3 * FB + SPC);
    unsigned short* VThi = (unsigned short*)(base + 4 * FB);
    unsigned short* VTlo = (unsigned short*)(base + 4 * FB + SPC);
    float* h1f = (float*)(base + 3 * FB);   // reuses K region (free after attn)

    // weight area: We1(4MB) We2(4MB) QKV(12MB) Wo(4MB) Wr1(4MB) = 28MB
    char* wp = base + 5 * FB;
    unsigned short* We1hi = (unsigned short*)(wp);
    unsigned short* We1lo = (unsigned short*)(wp + 2 * MB);
    unsigned short* We2hi = (unsigned short*)(wp + 4 * MB);
    unsigned short* We2lo = (unsigned short*)(wp + 6 * MB);
    unsigned short* QKVhi = (unsigned short*)(wp + 8 * MB);
    unsigned short* QKVlo = (unsigned short*)(wp + 14 * MB);
    unsigned short* Wohi  = (unsigned short*)(wp + 20 * MB);
    unsigned short* Wolo  = (unsigned short*)(wp + 22 * MB);
    unsigned short* Wr1hi = (unsigned short*)(wp + 24 * MB);
    unsigned short* Wr1lo = (unsigned short*)(wp + 26 * MB);
    char* smalls = wp + 28 * MB;
    float* wr2t    = (float*)smalls;
    float* seas24  = wr2t + 8192;
    float* seasons = seas24 + 6144;
    float* logits  = seasons + 2048;

    const size_t NEC = (size_t)N_TOK * E_EXP * CAPV;
    const float QSCALE = 0.08838834764831845f;

    float* OP = out;                                   // attn partial scratch (overwritten by fill)
    float* ML = out + (size_t)2 * 16 * 2048 * 128;

    dim3 blk(256);

    prep_k<<<4160, 256, 0, stream>>>(hid, B1hi, B1lo, Ws1, bs1, Ws2, bs2,
                                     seasons, seas24, Wr2, wr2t);

    WBatch wb;
    wb.src[0] = We1; wb.dh[0] = We1hi; wb.dl[0] = We1lo;
    wb.src[1] = We2; wb.dh[1] = We2hi; wb.dl[1] = We2lo;
    wb.src[2] = Wq;  wb.dh[2] = QKVhi;                     wb.dl[2] = QKVlo;
    wb.src[3] = Wk;  wb.dh[3] = QKVhi + (size_t)1024 * 1024;  wb.dl[3] = QKVlo + (size_t)1024 * 1024;
    wb.src[4] = Wv;  wb.dh[4] = QKVhi + (size_t)2048 * 1024;  wb.dl[4] = QKVlo + (size_t)2048 * 1024;
    wb.src[5] = Wo;  wb.dh[5] = Wohi;  wb.dl[5] = Wolo;
    wb.src[6] = Wr1; wb.dh[6] = Wr1hi; wb.dl[6] = Wr1lo;
    wconv_batch_k<<<dim3(16, 16, 7), blk, 0, stream>>>(wb);

    gemm_split<1, 0, 1, 0><<<512, blk, 0, stream>>>(B1hi, B1lo, We1hi, We1lo, be1,
        nullptr, B2hi, B2lo,
        We1 + (size_t)1024 * 1024, We1 + (size_t)1025 * 1024, seasons, nullptr, nullptr, 1.f);
    gemm_split<2, 0, 1, 0><<<512, blk, 0, stream>>>(B2hi, B2lo, We2hi, We2lo, be2,
        nullptr, B1hi, B1lo, nullptr, nullptr, nullptr, pos, seas24, 1.f);

    gemm_qkv<<<1536, blk, 0, stream>>>(B1hi, B1lo, QKVhi, QKVlo, bq, bk, bv,
                                       Qhi, Qlo, Khi, Klo, VThi, VTlo, QSCALE);

    attn_mfma_k<<<1024, 256, 0, stream>>>(Qhi, Qlo, Khi, Klo, VThi, VTlo, OP, ML);
    attn_combine_k<<<2048, 256, 0, stream>>>(OP, ML, B2hi, B2lo);

    // zero-fill dispatch+combine (403MB) at streaming-write peak; must follow combine
    fill_k<<<2048, 256, 0, stream>>>(out);

    gemm_split<0, 0, 1, 0><<<512, blk, 0, stream>>>(B2hi, B2lo, Wohi, Wolo, bo,
        nullptr, B1hi, B1lo, nullptr, nullptr, nullptr, nullptr, nullptr, 1.f);
    gemm_split<3, 1, 0, 0><<<512, blk, 0, stream>>>(B1hi, B1lo, Wr1hi, Wr1lo, br1,
        h1f, nullptr, nullptr, nullptr, nullptr, nullptr, nullptr, nullptr, 1.f);

    logits_k<<<512, 256, 0, stream>>>(h1f, wr2t, br2, logits);
    topk_scatter_k<<<16, 256, 0, stream>>>(logits, out);
    aux_k<<<1, 256, 0, stream>>>(out + 2 * NEC, out + 2 * NEC + (size_t)N_TOK * E_EXP);
}

// Round 12
// 565.807 us; speedup vs baseline: 1.2017x; 1.0592x over previous
//
#include <hip/hip_runtime.h>
#include <hip/hip_fp16.h>
#include <math.h>

#define N_TOK 4096
#define S_LEN 2048
#define H_DIM 1024
#define E_EXP 8
#define CAPV  1536
#define NHEAD 8
#define HDHD  128

// d_out scratch: OP (2*16*2048*128 f32) + ML (2*16*2048*2 f32) = 8,519,680 floats
#define SCRATCH_F4 2129920u            // = 8,519,680 / 4
#define TOTAL_F4   25165824u           // = 2*NEC / 4

typedef __attribute__((ext_vector_type(8))) _Float16 v8h;
typedef __attribute__((ext_vector_type(4))) float v4f;

__device__ __forceinline__ void splitf16(float v, unsigned short& h, unsigned short& l) {
    __half hh = __float2half(v);
    h = __half_as_ushort(hh);
    l = __half_as_ushort(__float2half(v - __half2float(hh)));
}

__device__ __forceinline__ void gld_lds16(const void* g, void* l) {
    __builtin_amdgcn_global_load_lds(
        (const __attribute__((address_space(1))) unsigned int*)g,
        (__attribute__((address_space(3))) unsigned int*)l,
        16, 0, 0);
}

// ---------------------------------------------------------------- fused prep
__global__ __launch_bounds__(256) void prep_k(
    const float* __restrict__ hid, unsigned short* __restrict__ hi,
    unsigned short* __restrict__ lo,
    const float* __restrict__ Ws1, const float* __restrict__ bs1,
    const float* __restrict__ Ws2, const float* __restrict__ bs2,
    float* __restrict__ seasons, float* __restrict__ seas24,
    const float* __restrict__ Wr2, float* __restrict__ wr2t) {
    __shared__ float hbuf[256];
    int blk = blockIdx.x;
    int tid = threadIdx.x;
    if (blk < 4096) {
        int i = blk * 256 + tid;
        float4 v = ((const float4*)hid)[i];
        ushort4 h, l;
        splitf16(v.x, h.x, l.x);
        splitf16(v.y, h.y, l.y);
        splitf16(v.z, h.z, l.z);
        splitf16(v.w, h.w, l.w);
        ((ushort4*)hi)[i] = h;
        ((ushort4*)lo)[i] = l;
    } else if (blk < 4104) {
        int s = (blk - 4096) * 256 + tid;
        if (s < S_LEN) {
            double a = (double)s * 2.0 * M_PI / 24.0;
            seasons[s] = (float)sin(a);
        }
    } else if (blk < 4128) {
        int m = blk - 4104;
        double a = (double)m * 2.0 * M_PI / 24.0;
        float sv = (float)sin(a);
        int j = tid;
        hbuf[j] = fmaxf(sv * Ws1[j] + bs1[j], 0.f);
        __syncthreads();
        float acc = bs2[j];
        for (int i = 0; i < 256; ++i) acc = fmaf(hbuf[i], Ws2[i * 256 + j], acc);
        seas24[m * 256 + j] = acc;
    } else {
        int i = (blk - 4128) * 256 + tid;
        int k = i >> 3, e = i & 7;
        wr2t[e * 1024 + k] = Wr2[i];
    }
}

// ---------------------------------------------------------------- W[1024][1024] -> W^T hi/lo f16
__device__ __forceinline__ void wconv_body(const float* __restrict__ W,
                                           unsigned short* __restrict__ Thi,
                                           unsigned short* __restrict__ Tlo) {
    __shared__ unsigned short Hs[64][65];
    __shared__ unsigned short Ls[64][65];
    int k0 = blockIdx.y * 64, n0 = blockIdx.x * 64;
    int tid = threadIdx.x;
#pragma unroll
    for (int i = 0; i < 4; ++i) {
        int idx = tid + i * 256;
        int kk = idx >> 4, n4 = idx & 15;
        float4 v = *(const float4*)(W + (size_t)(k0 + kk) * 1024 + n0 + n4 * 4);
        unsigned short h, l;
        splitf16(v.x, h, l); Hs[n4 * 4 + 0][kk] = h; Ls[n4 * 4 + 0][kk] = l;
        splitf16(v.y, h, l); Hs[n4 * 4 + 1][kk] = h; Ls[n4 * 4 + 1][kk] = l;
        splitf16(v.z, h, l); Hs[n4 * 4 + 2][kk] = h; Ls[n4 * 4 + 2][kk] = l;
        splitf16(v.w, h, l); Hs[n4 * 4 + 3][kk] = h; Ls[n4 * 4 + 3][kk] = l;
    }
    __syncthreads();
#pragma unroll
    for (int i = 0; i < 4; ++i) {
        int idx = tid + i * 256;
        int n = idx >> 4, k4 = idx & 15;
        ushort4 h = make_ushort4(Hs[n][k4 * 4], Hs[n][k4 * 4 + 1], Hs[n][k4 * 4 + 2], Hs[n][k4 * 4 + 3]);
        ushort4 l = make_ushort4(Ls[n][k4 * 4], Ls[n][k4 * 4 + 1], Ls[n][k4 * 4 + 2], Ls[n][k4 * 4 + 3]);
        *(ushort4*)(Thi + (size_t)(n0 + n) * 1024 + k0 + k4 * 4) = h;
        *(ushort4*)(Tlo + (size_t)(n0 + n) * 1024 + k0 + k4 * 4) = l;
    }
}

struct WBatch {
    const float* src[7];
    unsigned short* dh[7];
    unsigned short* dl[7];
};

__global__ __launch_bounds__(256) void wconv_batch_k(WBatch wb) {
    int i = blockIdx.z;
    wconv_body(wb.src[i], wb.dh[i], wb.dl[i]);
}

// ---------------------------------------------------------------- co-scheduled fill body
// grid-stride NT zero-fill of f4 range [f40, f41) using nblk blocks.
__device__ __forceinline__ void fill_body(float* __restrict__ p, size_t f40, size_t f41, int nblk) {
    v4f z = {0.f, 0.f, 0.f, 0.f};
    v4f* o = (v4f*)p;
    size_t n = f41 - f40;
    for (size_t i = (size_t)blockIdx.x * 256 + threadIdx.x; i < n; i += (size_t)nblk * 256)
        __builtin_nontemporal_store(z, o + f40 + i);
}

// ---------------------------------------------------------------- split-f16 MFMA GEMM (dbuf + XCD swizzle)
// FILLN>0: first FILLN blocks zero-fill fillp f4 [0, SCRATCH_F4) and exit.
template <int MODE, int EMITF, int EMITS, int EMITT, int FILLN>
__global__ __launch_bounds__(256, 2) void gemm_split(
    const unsigned short* __restrict__ Ahi, const unsigned short* __restrict__ Alo,
    const unsigned short* __restrict__ WThi, const unsigned short* __restrict__ WTlo,
    const float* __restrict__ bias, float* __restrict__ Cf,
    unsigned short* __restrict__ Chi, unsigned short* __restrict__ Clo,
    const float* __restrict__ rowT, const float* __restrict__ rowS,
    const float* __restrict__ seasons, const float* __restrict__ pos,
    const float* __restrict__ seas24, float escale, float* __restrict__ fillp) {
    if (FILLN > 0) {
        if (blockIdx.x < (unsigned)FILLN) {
            fill_body(fillp, 0, SCRATCH_F4, FILLN);
            return;
        }
    }
    __shared__ unsigned short Ash[2][128 * 32];
    __shared__ unsigned short Asl[2][128 * 32];
    __shared__ unsigned short Bsh[2][64 * 32];
    __shared__ unsigned short Bsl[2][64 * 32];
    int tid = threadIdx.x;
    int lane = tid & 63, w = tid >> 6;
    int l15 = lane & 15, l16 = lane >> 4;
    int wm = (w >> 1) * 64, wn = (w & 1) * 32;

    int bid = blockIdx.x - FILLN;
    int mp = (bid & 7) + ((bid >> 7) << 3);
    int np = (bid >> 3) & 15;
    int m0 = mp * 128, n0 = np * 64;

    int ac0 = w * 128 + lane;
    int ac1 = ac0 + 64;
    int bc  = w * 64 + lane;
    int ar0 = ac0 >> 2, ar1 = ac1 >> 2, bn = bc >> 2;
    size_t a_src0 = (size_t)(m0 + ar0) * 1024 + (((ac0 & 3) ^ (ar0 & 3)) * 8);
    size_t a_src1 = (size_t)(m0 + ar1) * 1024 + (((ac1 & 3) ^ (ar1 & 3)) * 8);
    size_t b_src  = (size_t)(n0 + bn) * 1024 + (((bc & 3) ^ (bn & 3)) * 8);

    int a_off[4], b_off[2];
#pragma unroll
    for (int mi = 0; mi < 4; ++mi) {
        int row = wm + mi * 16 + l15;
        a_off[mi] = row * 32 + ((l16 ^ (row & 3)) * 8);
    }
#pragma unroll
    for (int ni = 0; ni < 2; ++ni) {
        int n = wn + ni * 16 + l15;
        b_off[ni] = n * 32 + ((l16 ^ (n & 3)) * 8);
    }

    auto STAGE = [&](int buf, int k0) {
        gld_lds16(Ahi + a_src0 + k0, &Ash[buf][ac0 * 8]);
        gld_lds16(Ahi + a_src1 + k0, &Ash[buf][ac1 * 8]);
        gld_lds16(Alo + a_src0 + k0, &Asl[buf][ac0 * 8]);
        gld_lds16(Alo + a_src1 + k0, &Asl[buf][ac1 * 8]);
        gld_lds16(WThi + b_src + k0, &Bsh[buf][bc * 8]);
        gld_lds16(WTlo + b_src + k0, &Bsl[buf][bc * 8]);
    };

    v4f acc[4][2] = {};
    STAGE(0, 0);
    __syncthreads();

    for (int kk = 0; kk < 32; ++kk) {
        int cur = kk & 1;
        if (kk < 31) STAGE(cur ^ 1, (kk + 1) * 32);
        v8h ah[4], al[4], bh[2], bl[2];
#pragma unroll
        for (int mi = 0; mi < 4; ++mi) {
            ah[mi] = *(const v8h*)&Ash[cur][a_off[mi]];
            al[mi] = *(const v8h*)&Asl[cur][a_off[mi]];
        }
#pragma unroll
        for (int ni = 0; ni < 2; ++ni) {
            bh[ni] = *(const v8h*)&Bsh[cur][b_off[ni]];
            bl[ni] = *(const v8h*)&Bsl[cur][b_off[ni]];
        }
#pragma unroll
        for (int mi = 0; mi < 4; ++mi)
#pragma unroll
            for (int ni = 0; ni < 2; ++ni) {
                acc[mi][ni] = __builtin_amdgcn_mfma_f32_16x16x32_f16(ah[mi], bh[ni], acc[mi][ni], 0, 0, 0);
                acc[mi][ni] = __builtin_amdgcn_mfma_f32_16x16x32_f16(al[mi], bh[ni], acc[mi][ni], 0, 0, 0);
                acc[mi][ni] = __builtin_amdgcn_mfma_f32_16x16x32_f16(ah[mi], bl[ni], acc[mi][ni], 0, 0, 0);
            }
        __syncthreads();
    }

    if (EMITT) {
#pragma unroll
        for (int mi = 0; mi < 4; ++mi) {
            int row0 = m0 + wm + mi * 16 + l16 * 4;
            int bb = row0 >> 11, ss = row0 & 2047;
#pragma unroll
            for (int ni = 0; ni < 2; ++ni) {
                int col = n0 + wn + ni * 16 + l15;
                int hh = col >> 7, dd = col & 127;
                size_t base = ((size_t)((bb * 8 + hh) * 128 + dd)) * 2048 + ss;
                ushort4 vh, vl;
                float v0 = acc[mi][ni][0] + bias[col];
                float v1 = acc[mi][ni][1] + bias[col];
                float v2 = acc[mi][ni][2] + bias[col];
                float v3 = acc[mi][ni][3] + bias[col];
                splitf16(v0, vh.x, vl.x);
                splitf16(v1, vh.y, vl.y);
                splitf16(v2, vh.z, vl.z);
                splitf16(v3, vh.w, vl.w);
                *(ushort4*)(Chi + base) = vh;
                *(ushort4*)(Clo + base) = vl;
            }
        }
    } else {
#pragma unroll
        for (int mi = 0; mi < 4; ++mi) {
#pragma unroll
            for (int r = 0; r < 4; ++r) {
                int row = m0 + wm + mi * 16 + l16 * 4 + r;
                int s = row & (S_LEN - 1);
                float tval = 0.f, seval = 0.f;
                if (MODE == 1) { tval = (float)s; seval = seasons[s]; }
#pragma unroll
                for (int ni = 0; ni < 2; ++ni) {
                    int col = n0 + wn + ni * 16 + l15;
                    float v = acc[mi][ni][r] + bias[col];
                    if (MODE == 1) v += tval * rowT[col] + seval * rowS[col];
                    if (MODE == 2) v += pos[(size_t)s * 1024 + col] + seas24[(s % 24) * 256 + (col & 255)];
                    if (MODE == 1 || MODE == 3) v = fmaxf(v, 0.f);
                    size_t o = (size_t)row * 1024 + col;
                    if (EMITF) Cf[o] = v;
                    if (EMITS) {
                        unsigned short hu, lu;
                        splitf16(v * escale, hu, lu);
                        Chi[o] = hu; Clo[o] = lu;
                    }
                }
            }
        }
    }
}

// ---------------------------------------------------------------- fused QKV GEMM + co-scheduled big fill
// blocks [0,256): NT zero-fill of out f4 [SCRATCH_F4, TOTAL_F4)  (368 MB)
// blocks [256,1792): QKV gemm (bid-256 decoded as before; 256%8==0 keeps XCD map)
#define NFILLQ 256
__global__ __launch_bounds__(256, 2) void gemm_qkv(
    const unsigned short* __restrict__ Ahi, const unsigned short* __restrict__ Alo,
    const unsigned short* __restrict__ WT3hi, const unsigned short* __restrict__ WT3lo,
    const float* __restrict__ bq, const float* __restrict__ bk,
    const float* __restrict__ bv,
    unsigned short* __restrict__ Qhi, unsigned short* __restrict__ Qlo,
    unsigned short* __restrict__ Khi, unsigned short* __restrict__ Klo,
    unsigned short* __restrict__ VThi, unsigned short* __restrict__ VTlo,
    float qscale, float* __restrict__ fillp) {
    if (blockIdx.x < NFILLQ) {
        fill_body(fillp, SCRATCH_F4, TOTAL_F4, NFILLQ);
        return;
    }
    __shared__ unsigned short Ash[2][128 * 32];
    __shared__ unsigned short Asl[2][128 * 32];
    __shared__ unsigned short Bsh[2][64 * 32];
    __shared__ unsigned short Bsl[2][64 * 32];
    int tid = threadIdx.x;
    int lane = tid & 63, w = tid >> 6;
    int l15 = lane & 15, l16 = lane >> 4;
    int wm = (w >> 1) * 64, wn = (w & 1) * 32;

    int bid = blockIdx.x - NFILLQ;
    int t = bid >> 3;
    int mp = (bid & 7) + (t / 48) * 8;
    int np = t % 48;
    int m0 = mp * 128;
    int wn0 = np * 64;

    int ac0 = w * 128 + lane;
    int ac1 = ac0 + 64;
    int bc  = w * 64 + lane;
    int ar0 = ac0 >> 2, ar1 = ac1 >> 2, bn = bc >> 2;
    size_t a_src0 = (size_t)(m0 + ar0) * 1024 + (((ac0 & 3) ^ (ar0 & 3)) * 8);
    size_t a_src1 = (size_t)(m0 + ar1) * 1024 + (((ac1 & 3) ^ (ar1 & 3)) * 8);
    size_t b_src  = (size_t)(wn0 + bn) * 1024 + (((bc & 3) ^ (bn & 3)) * 8);

    int a_off[4], b_off[2];
#pragma unroll
    for (int mi = 0; mi < 4; ++mi) {
        int row = wm + mi * 16 + l15;
        a_off[mi] = row * 32 + ((l16 ^ (row & 3)) * 8);
    }
#pragma unroll
    for (int ni = 0; ni < 2; ++ni) {
        int n = wn + ni * 16 + l15;
        b_off[ni] = n * 32 + ((l16 ^ (n & 3)) * 8);
    }

    auto STAGE = [&](int buf, int k0) {
        gld_lds16(Ahi + a_src0 + k0, &Ash[buf][ac0 * 8]);
        gld_lds16(Ahi + a_src1 + k0, &Ash[buf][ac1 * 8]);
        gld_lds16(Alo + a_src0 + k0, &Asl[buf][ac0 * 8]);
        gld_lds16(Alo + a_src1 + k0, &Asl[buf][ac1 * 8]);
        gld_lds16(WT3hi + b_src + k0, &Bsh[buf][bc * 8]);
        gld_lds16(WT3lo + b_src + k0, &Bsl[buf][bc * 8]);
    };

    v4f acc[4][2] = {};
    STAGE(0, 0);
    __syncthreads();

    for (int kk = 0; kk < 32; ++kk) {
        int cur = kk & 1;
        if (kk < 31) STAGE(cur ^ 1, (kk + 1) * 32);
        v8h ah[4], al[4], bh[2], bl[2];
#pragma unroll
        for (int mi = 0; mi < 4; ++mi) {
            ah[mi] = *(const v8h*)&Ash[cur][a_off[mi]];
            al[mi] = *(const v8h*)&Asl[cur][a_off[mi]];
        }
#pragma unroll
        for (int ni = 0; ni < 2; ++ni) {
            bh[ni] = *(const v8h*)&Bsh[cur][b_off[ni]];
            bl[ni] = *(const v8h*)&Bsl[cur][b_off[ni]];
        }
#pragma unroll
        for (int mi = 0; mi < 4; ++mi)
#pragma unroll
            for (int ni = 0; ni < 2; ++ni) {
                acc[mi][ni] = __builtin_amdgcn_mfma_f32_16x16x32_f16(ah[mi], bh[ni], acc[mi][ni], 0, 0, 0);
                acc[mi][ni] = __builtin_amdgcn_mfma_f32_16x16x32_f16(al[mi], bh[ni], acc[mi][ni], 0, 0, 0);
                acc[mi][ni] = __builtin_amdgcn_mfma_f32_16x16x32_f16(ah[mi], bl[ni], acc[mi][ni], 0, 0, 0);
            }
        __syncthreads();
    }

    if (np >= 32) {
        const float* bias = bv;
        int n0 = (np - 32) * 64;
#pragma unroll
        for (int mi = 0; mi < 4; ++mi) {
            int row0 = m0 + wm + mi * 16 + l16 * 4;
            int bb = row0 >> 11, ss = row0 & 2047;
#pragma unroll
            for (int ni = 0; ni < 2; ++ni) {
                int col = n0 + wn + ni * 16 + l15;
                int hh = col >> 7, dd = col & 127;
                size_t base = ((size_t)((bb * 8 + hh) * 128 + dd)) * 2048 + ss;
                ushort4 vh, vl;
                float v0 = acc[mi][ni][0] + bias[col];
                float v1 = acc[mi][ni][1] + bias[col];
                float v2 = acc[mi][ni][2] + bias[col];
                float v3 = acc[mi][ni][3] + bias[col];
                splitf16(v0, vh.x, vl.x);
                splitf16(v1, vh.y, vl.y);
                splitf16(v2, vh.z, vl.z);
                splitf16(v3, vh.w, vl.w);
                *(ushort4*)(VThi + base) = vh;
                *(ushort4*)(VTlo + base) = vl;
            }
        }
    } else {
        const float* bias = np < 16 ? bq : bk;
        unsigned short* Dhi = np < 16 ? Qhi : Khi;
        unsigned short* Dlo = np < 16 ? Qlo : Klo;
        float esc = np < 16 ? qscale : 1.f;
        int n0 = (np & 15) * 64;
#pragma unroll
        for (int mi = 0; mi < 4; ++mi) {
#pragma unroll
            for (int r = 0; r < 4; ++r) {
                int row = m0 + wm + mi * 16 + l16 * 4 + r;
#pragma unroll
                for (int ni = 0; ni < 2; ++ni) {
                    int col = n0 + wn + ni * 16 + l15;
                    float v = (acc[mi][ni][r] + bias[col]) * esc;
                    size_t o = (size_t)row * 1024 + col;
                    unsigned short hu, lu;
                    splitf16(v, hu, lu);
                    Dhi[o] = hu; Dlo[o] = lu;
                }
            }
        }
    }
}

// ---------------------------------------------------------------- MFMA attention v4 + XCD swizzle
__global__ __launch_bounds__(256, 4) void attn_mfma_k(
    const unsigned short* __restrict__ qhi, const unsigned short* __restrict__ qlo,
    const unsigned short* __restrict__ khi, const unsigned short* __restrict__ klo,
    const unsigned short* __restrict__ vthi, const unsigned short* __restrict__ vtlo,
    float* __restrict__ OP, float* __restrict__ ML) {
    __shared__ unsigned short Ks_hi[32 * 128];
    __shared__ unsigned short Ks_lo[32 * 128];
    __shared__ unsigned short Vs_hi[128 * 32];
    __shared__ unsigned short Vs_lo[128 * 32];
    __shared__ unsigned int   Ps[64 * 32];

    int p = blockIdx.x;
    int x = (p >> 3) & 31;
    int g = (p & 7) + ((p >> 8) << 3);
    int bh = g >> 1, z = g & 1;
    int b = bh >> 3, h = bh & 7;
    int q0 = x * 64;
    int tid = threadIdx.x;
    int lane = tid & 63, w = tid >> 6;
    int l15 = lane & 15, l16 = lane >> 4;
    int wm = w * 16;

    v8h qa_h[4], qa_l[4];
    {
        size_t qrow = (size_t)(b * S_LEN + q0 + wm + l15) * H_DIM + h * HDHD;
#pragma unroll
        for (int ks = 0; ks < 4; ++ks) {
            qa_h[ks] = *(const v8h*)(qhi + qrow + ks * 32 + l16 * 8);
            qa_l[ks] = *(const v8h*)(qlo + qrow + ks * 32 + l16 * 8);
        }
    }

    int ktok1 = tid >> 4, kslot1 = tid & 15;
    int ktok2 = ktok1 + 16;
    size_t ksrc1 = (size_t)(b * S_LEN + ktok1) * H_DIM + h * HDHD + ((kslot1 ^ (ktok1 & 7)) * 8);
    size_t ksrc2 = (size_t)(b * S_LEN + ktok2) * H_DIM + h * HDHD + ((kslot1 ^ (ktok2 & 7)) * 8);
    int vd1 = tid >> 2, vslot1 = tid & 3;
    int vd2 = vd1 + 64;
    size_t vsrc1 = (size_t)(bh * HDHD + vd1) * S_LEN + ((vslot1 ^ ((vd1 >> 1) & 3)) * 8);
    size_t vsrc2 = (size_t)(bh * HDHD + vd2) * S_LEN + ((vslot1 ^ ((vd2 >> 1) & 3)) * 8);

    v4f accO[8] = {};
    float mreg[4] = {-1e30f, -1e30f, -1e30f, -1e30f};
    float lreg[4] = {};

    int kt0 = z * 1024;
    for (int it = 0; it < 32; ++it) {
        int kt = kt0 + it * 32;
        __syncthreads();
        size_t koff = (size_t)kt * H_DIM;
        gld_lds16(khi + ksrc1 + koff, &Ks_hi[tid * 8]);
        gld_lds16(khi + ksrc2 + koff, &Ks_hi[(tid + 256) * 8]);
        gld_lds16(klo + ksrc1 + koff, &Ks_lo[tid * 8]);
        gld_lds16(klo + ksrc2 + koff, &Ks_lo[(tid + 256) * 8]);
        gld_lds16(vthi + vsrc1 + kt, &Vs_hi[tid * 8]);
        gld_lds16(vthi + vsrc2 + kt, &Vs_hi[(tid + 256) * 8]);
        gld_lds16(vtlo + vsrc1 + kt, &Vs_lo[tid * 8]);
        gld_lds16(vtlo + vsrc2 + kt, &Vs_lo[(tid + 256) * 8]);
        __syncthreads();

        v4f s0 = {}, s1 = {};
#pragma unroll
        for (int ks = 0; ks < 4; ++ks) {
#pragma unroll
            for (int nt = 0; nt < 2; ++nt) {
                int tok = nt * 16 + l15;
                int slot = (ks * 4 + l16) ^ (tok & 7);
                v8h bhf = *(const v8h*)&Ks_hi[tok * 128 + slot * 8];
                v8h blf = *(const v8h*)&Ks_lo[tok * 128 + slot * 8];
                v4f& ss = nt ? s1 : s0;
                ss = __builtin_amdgcn_mfma_f32_16x16x32_f16(qa_h[ks], bhf, ss, 0, 0, 0);
                ss = __builtin_amdgcn_mfma_f32_16x16x32_f16(qa_l[ks], bhf, ss, 0, 0, 0);
                ss = __builtin_amdgcn_mfma_f32_16x16x32_f16(qa_h[ks], blf, ss, 0, 0, 0);
            }
        }

        float p0[4], p1[4], alpha[4];
#pragma unroll
        for (int r = 0; r < 4; ++r) {
            float tmax = fmaxf(s0[r], s1[r]);
            tmax = fmaxf(tmax, __shfl_xor(tmax, 1));
            tmax = fmaxf(tmax, __shfl_xor(tmax, 2));
            tmax = fmaxf(tmax, __shfl_xor(tmax, 4));
            tmax = fmaxf(tmax, __shfl_xor(tmax, 8));
            float mnew = fmaxf(mreg[r], tmax);
            alpha[r] = __expf(mreg[r] - mnew);
            p0[r] = __expf(s0[r] - mnew);
            p1[r] = __expf(s1[r] - mnew);
            float lt = p0[r] + p1[r];
            lt += __shfl_xor(lt, 1);
            lt += __shfl_xor(lt, 2);
            lt += __shfl_xor(lt, 4);
            lt += __shfl_xor(lt, 8);
            lreg[r] = lreg[r] * alpha[r] + lt;
            mreg[r] = mnew;
        }
#pragma unroll
        for (int nt = 0; nt < 8; ++nt)
#pragma unroll
            for (int r = 0; r < 4; ++r) accO[nt][r] *= alpha[r];

#pragma unroll
        for (int r = 0; r < 4; ++r) {
            int qq = wm + l16 * 4 + r;
            unsigned short ph, pl;
            splitf16(p0[r], ph, pl);
            int k0i = l15;
            Ps[qq * 32 + ((((k0i >> 2) ^ (qq & 7)) << 2) | (k0i & 3))] =
                (unsigned)ph | ((unsigned)pl << 16);
            splitf16(p1[r], ph, pl);
            int k1i = 16 + l15;
            Ps[qq * 32 + ((((k1i >> 2) ^ (qq & 7)) << 2) | (k1i & 3))] =
                (unsigned)ph | ((unsigned)pl << 16);
        }

        int qq = wm + l15;
        int sA = (l16 * 2) ^ (qq & 7);
        int sB = (l16 * 2 + 1) ^ (qq & 7);
        uint4 ua = *(const uint4*)&Ps[qq * 32 + sA * 4];
        uint4 ub = *(const uint4*)&Ps[qq * 32 + sB * 4];
        uint4 ahw, alw;
        ahw.x = (ua.x & 0xffffu) | (ua.y << 16);
        ahw.y = (ua.z & 0xffffu) | (ua.w << 16);
        ahw.z = (ub.x & 0xffffu) | (ub.y << 16);
        ahw.w = (ub.z & 0xffffu) | (ub.w << 16);
        alw.x = (ua.x >> 16) | (ua.y & 0xffff0000u);
        alw.y = (ua.z >> 16) | (ua.w & 0xffff0000u);
        alw.z = (ub.x >> 16) | (ub.y & 0xffff0000u);
        alw.w = (ub.z >> 16) | (ub.w & 0xffff0000u);
        v8h pA_h = __builtin_bit_cast(v8h, ahw);
        v8h pA_l = __builtin_bit_cast(v8h, alw);
#pragma unroll
        for (int nt = 0; nt < 8; ++nt) {
            int d = nt * 16 + l15;
            int slot = l16 ^ ((d >> 1) & 3);
            v8h vhf = *(const v8h*)&Vs_hi[d * 32 + slot * 8];
            v8h vlf = *(const v8h*)&Vs_lo[d * 32 + slot * 8];
            accO[nt] = __builtin_amdgcn_mfma_f32_16x16x32_f16(pA_h, vhf, accO[nt], 0, 0, 0);
            accO[nt] = __builtin_amdgcn_mfma_f32_16x16x32_f16(pA_l, vhf, accO[nt], 0, 0, 0);
            accO[nt] = __builtin_amdgcn_mfma_f32_16x16x32_f16(pA_h, vlf, accO[nt], 0, 0, 0);
        }
    }

#pragma unroll
    for (int r = 0; r < 4; ++r) {
        if (l15 == 0) {
            int q = q0 + wm + l16 * 4 + r;
            size_t mlo = ((size_t)(z * 16 + bh) * 2048 + q) * 2;
            ML[mlo] = mreg[r];
            ML[mlo + 1] = lreg[r];
        }
    }
#pragma unroll
    for (int nt = 0; nt < 8; ++nt) {
#pragma unroll
        for (int r = 0; r < 4; ++r) {
            int q = q0 + wm + l16 * 4 + r;
            size_t o = ((size_t)(z * 16 + bh) * 2048 + q) * 128 + nt * 16 + l15;
            OP[o] = accO[nt][r];
        }
    }
}

// ---------------------------------------------------------------- flash combine
__global__ __launch_bounds__(256) void attn_combine_k(
    const float* __restrict__ OP, const float* __restrict__ ML,
    unsigned short* __restrict__ ctx_hi, unsigned short* __restrict__ ctx_lo) {
    int tid = threadIdx.x;
    int R = blockIdx.x * 16 + (tid >> 4);
    int bh = R >> 11, q = R & 2047;
    int b = bh >> 3, h = bh & 7;
    int d0 = (tid & 15) * 8;
    size_t ml0 = ((size_t)bh * 2048 + q) * 2;
    size_t ml1 = ((size_t)(16 + bh) * 2048 + q) * 2;
    float m0 = ML[ml0], l0 = ML[ml0 + 1];
    float m1 = ML[ml1], l1 = ML[ml1 + 1];
    float m = fmaxf(m0, m1);
    float w0 = __expf(m0 - m), w1 = __expf(m1 - m);
    float inv = 1.f / (w0 * l0 + w1 * l1);
    const float* O0 = OP + ((size_t)bh * 2048 + q) * 128 + d0;
    const float* O1 = OP + ((size_t)(16 + bh) * 2048 + q) * 128 + d0;
    size_t dst = ((size_t)(b * 2048 + q)) * 1024 + h * 128 + d0;
    float4 a0 = *(const float4*)O0;
    float4 a1 = *(const float4*)(O0 + 4);
    float4 c0 = *(const float4*)O1;
    float4 c1 = *(const float4*)(O1 + 4);
    ushort4 h0, h1, lo0, lo1;
    splitf16((w0 * a0.x + w1 * c0.x) * inv, h0.x, lo0.x);
    splitf16((w0 * a0.y + w1 * c0.y) * inv, h0.y, lo0.y);
    splitf16((w0 * a0.z + w1 * c0.z) * inv, h0.z, lo0.z);
    splitf16((w0 * a0.w + w1 * c0.w) * inv, h0.w, lo0.w);
    splitf16((w0 * a1.x + w1 * c1.x) * inv, h1.x, lo1.x);
    splitf16((w0 * a1.y + w1 * c1.y) * inv, h1.y, lo1.y);
    splitf16((w0 * a1.z + w1 * c1.z) * inv, h1.z, lo1.z);
    splitf16((w0 * a1.w + w1 * c1.w) * inv, h1.w, lo1.w);
    *(ushort4*)(ctx_hi + dst) = h0;
    *(ushort4*)(ctx_hi + dst + 4) = h1;
    *(ushort4*)(ctx_lo + dst) = lo0;
    *(ushort4*)(ctx_lo + dst + 4) = lo1;
}

// ---------------------------------------------------------------- router logits
__global__ __launch_bounds__(256) void logits_k(const float* __restrict__ h1,
                                                const float* __restrict__ Wr2T,
                                                const float* __restrict__ br2,
                                                float* __restrict__ logits) {
    __shared__ float part[256];
    int tid = threadIdx.x;
    int tok8 = tid >> 5;
    int e = (tid >> 2) & 7;
    int ch = tid & 3;
    int tok = blockIdx.x * 8 + tok8;
    const float4* h4 = (const float4*)(h1 + (size_t)tok * 1024 + ch * 256);
    const float4* w4 = (const float4*)(Wr2T + (size_t)e * 1024 + ch * 256);
    float acc = 0.f;
#pragma unroll
    for (int i = 0; i < 64; ++i) {
        float4 a = h4[i];
        float4 bb = w4[i];
        acc = fmaf(a.x, bb.x, fmaf(a.y, bb.y, fmaf(a.z, bb.z, fmaf(a.w, bb.w, acc))));
    }
    part[tid] = acc;
    __syncthreads();
    if (ch == 0) {
        float s = part[tid] + part[tid + 1] + part[tid + 2] + part[tid + 3] + br2[e];
        logits[(size_t)tok * 8 + e] = s;
    }
}

// ---------------------------------------------------------------- softmax + top2 scatter (after fills)
__global__ __launch_bounds__(256) void topk_scatter_k(const float* __restrict__ logits,
                                                      float* __restrict__ out) {
    int tok = blockIdx.x * 256 + threadIdx.x;
    if (tok >= N_TOK) return;
    float l[8], p[8];
    float mx = -1e30f;
#pragma unroll
    for (int e = 0; e < 8; ++e) { l[e] = logits[(size_t)tok * 8 + e]; mx = fmaxf(mx, l[e]); }
    float sum = 0.f;
#pragma unroll
    for (int e = 0; e < 8; ++e) { p[e] = __expf(l[e] - mx); sum += p[e]; }
    float inv = 1.f / sum;
#pragma unroll
    for (int e = 0; e < 8; ++e) p[e] *= inv;
    const size_t NEC = (size_t)N_TOK * E_EXP * CAPV;
    float* probs_out = out + 2 * NEC;
#pragma unroll
    for (int e = 0; e < 8; ++e) probs_out[(size_t)tok * 8 + e] = p[e];
    int i1 = 0;
#pragma unroll
    for (int e = 1; e < 8; ++e) if (p[e] > p[i1]) i1 = e;
    int i2 = -1;
#pragma unroll
    for (int e = 0; e < 8; ++e) {
        if (e == i1) continue;
        if (i2 < 0 || p[e] > p[i2]) i2 = e;
    }
    float v1 = p[i1], v2 = p[i2], tv = v1 + v2;
    size_t base = (size_t)tok * E_EXP * CAPV;
    out[base + (size_t)i1 * CAPV] = 1.f;
    out[base + (size_t)i2 * CAPV] = 1.f;
    out[NEC + base + (size_t)i1 * CAPV] = v1 / tv;
    out[NEC + base + (size_t)i2 * CAPV] = v2 / tv;
}

// ---------------------------------------------------------------- aux loss
__global__ void aux_k(const float* __restrict__ probs, float* __restrict__ out_aux) {
    __shared__ float part[256];
    int tid = threadIdx.x;
    int e = tid & 7, chunk = tid >> 3;
    float s = 0.f;
    for (int t = chunk * 128; t < (chunk + 1) * 128; ++t)
        s += probs[(size_t)t * 8 + e];
    part[tid] = s;
    __syncthreads();
    if (tid < 8) {
        float tot = 0.f;
        for (int c = 0; c < 32; ++c) tot += part[c * 8 + e];
        part[tid] = tot / (float)N_TOK;
    }
    __syncthreads();
    if (tid == 0) {
        float aux = 0.f;
        for (int e2 = 0; e2 < 8; ++e2) {
            float pm = part[e2];
            aux += pm * logf(pm * 8.f + 1e-9f);
        }
        *out_aux = aux;
    }
}

// ---------------------------------------------------------------- launch
extern "C" void kernel_launch(void* const* d_in, const int* in_sizes, int n_in,
                              void* d_out, int out_size, void* d_ws, size_t ws_size,
                              hipStream_t stream) {
    const float* hid = (const float*)d_in[0];
    const float* pos = (const float*)d_in[1];
    const float* We1 = (const float*)d_in[2];
    const float* be1 = (const float*)d_in[3];
    const float* We2 = (const float*)d_in[4];
    const float* be2 = (const float*)d_in[5];
    const float* Ws1 = (const float*)d_in[6];
    const float* bs1 = (const float*)d_in[7];
    const float* Ws2 = (const float*)d_in[8];
    const float* bs2 = (const float*)d_in[9];
    const float* Wq  = (const float*)d_in[10]; const float* bq = (const float*)d_in[11];
    const float* Wk  = (const float*)d_in[12]; const float* bk = (const float*)d_in[13];
    const float* Wv  = (const float*)d_in[14]; const float* bv = (const float*)d_in[15];
    const float* Wo  = (const float*)d_in[16]; const float* bo = (const float*)d_in[17];
    const float* Wr1 = (const float*)d_in[18]; const float* br1 = (const float*)d_in[19];
    const float* Wr2 = (const float*)d_in[20]; const float* br2 = (const float*)d_in[21];

    float* out = (float*)d_out;
    char* base = (char*)d_ws;
    const size_t AC  = (size_t)N_TOK * H_DIM;
    const size_t SPC = AC * 2;
    const size_t FB  = AC * 4;
    const size_t MB  = (size_t)1 << 20;

    unsigned short* B1hi = (unsigned short*)(base);
    unsigned short* B1lo = (unsigned short*)(base + SPC);
    unsigned short* B2hi = (unsigned short*)(base + FB);
    unsigned short* B2lo = (unsigned short*)(base + FB + SPC);
    unsigned short* Qhi  = (unsigned short*)(base + 2 * FB);
    unsigned short* Qlo  = (unsigned short*)(base + 2 * FB + SPC);
    unsigned short* Khi  = (unsigned short*)(base + 3 * FB);
    unsigned short* Klo  = (unsigned short*)(base + 3 * FB + SPC);
    unsigned short* VThi = (unsigned short*)(base + 4 * FB);
    unsigned short* VTlo = (unsigned short*)(base + 4 * FB + SPC);
    float* h1f = (float*)(base + 3 * FB);   // reuses K region (free after attn)

    char* wp = base + 5 * FB;
    unsigned short* We1hi = (unsigned short*)(wp);
    unsigned short* We1lo = (unsigned short*)(wp + 2 * MB);
    unsigned short* We2hi = (unsigned short*)(wp + 4 * MB);
    unsigned short* We2lo = (unsigned short*)(wp + 6 * MB);
    unsigned short* QKVhi = (unsigned short*)(wp + 8 * MB);
    unsigned short* QKVlo = (unsigned short*)(wp + 14 * MB);
    unsigned short* Wohi  = (unsigned short*)(wp + 20 * MB);
    unsigned short* Wolo  = (unsigned short*)(wp + 22 * MB);
    unsigned short* Wr1hi = (unsigned short*)(wp + 24 * MB);
    unsigned short* Wr1lo = (unsigned short*)(wp + 26 * MB);
    char* smalls = wp + 28 * MB;
    float* wr2t    = (float*)smalls;
    float* seas24  = wr2t + 8192;
    float* seasons = seas24 + 6144;
    float* logits  = seasons + 2048;

    const size_t NEC = (size_t)N_TOK * E_EXP * CAPV;
    const float QSCALE = 0.08838834764831845f;

    float* OP = out;                                   // scratch in d_out (zeroed by Wo-launch fill)
    float* ML = out + (size_t)2 * 16 * 2048 * 128;

    dim3 blk(256);

    prep_k<<<4160, 256, 0, stream>>>(hid, B1hi, B1lo, Ws1, bs1, Ws2, bs2,
                                     seasons, seas24, Wr2, wr2t);

    WBatch wb;
    wb.src[0] = We1; wb.dh[0] = We1hi; wb.dl[0] = We1lo;
    wb.src[1] = We2; wb.dh[1] = We2hi; wb.dl[1] = We2lo;
    wb.src[2] = Wq;  wb.dh[2] = QKVhi;                        wb.dl[2] = QKVlo;
    wb.src[3] = Wk;  wb.dh[3] = QKVhi + (size_t)1024 * 1024;  wb.dl[3] = QKVlo + (size_t)1024 * 1024;
    wb.src[4] = Wv;  wb.dh[4] = QKVhi + (size_t)2048 * 1024;  wb.dl[4] = QKVlo + (size_t)2048 * 1024;
    wb.src[5] = Wo;  wb.dh[5] = Wohi;  wb.dl[5] = Wolo;
    wb.src[6] = Wr1; wb.dh[6] = Wr1hi; wb.dl[6] = Wr1lo;
    wconv_batch_k<<<dim3(16, 16, 7), blk, 0, stream>>>(wb);

    gemm_split<1, 0, 1, 0, 0><<<512, blk, 0, stream>>>(B1hi, B1lo, We1hi, We1lo, be1,
        nullptr, B2hi, B2lo,
        We1 + (size_t)1024 * 1024, We1 + (size_t)1025 * 1024, seasons, nullptr, nullptr, 1.f, nullptr);
    gemm_split<2, 0, 1, 0, 0><<<512, blk, 0, stream>>>(B2hi, B2lo, We2hi, We2lo, be2,
        nullptr, B1hi, B1lo, nullptr, nullptr, nullptr, pos, seas24, 1.f, nullptr);

    // QKV gemm + co-scheduled big fill (368 MB of dispatch/combine region)
    gemm_qkv<<<1536 + NFILLQ, blk, 0, stream>>>(B1hi, B1lo, QKVhi, QKVlo, bq, bk, bv,
                                                Qhi, Qlo, Khi, Klo, VThi, VTlo, QSCALE, out);

    attn_mfma_k<<<1024, 256, 0, stream>>>(Qhi, Qlo, Khi, Klo, VThi, VTlo, OP, ML);
    attn_combine_k<<<2048, 256, 0, stream>>>(OP, ML, B2hi, B2lo);

    // Wo gemm + co-scheduled small fill (34 MB scratch region, now consumed)
    gemm_split<0, 0, 1, 0, 64><<<512 + 64, blk, 0, stream>>>(B2hi, B2lo, Wohi, Wolo, bo,
        nullptr, B1hi, B1lo, nullptr, nullptr, nullptr, nullptr, nullptr, 1.f, out);
    gemm_split<3, 1, 0, 0, 0><<<512, blk, 0, stream>>>(B1hi, B1lo, Wr1hi, Wr1lo, br1,
        h1f, nullptr, nullptr, nullptr, nullptr, nullptr, nullptr, nullptr, 1.f, nullptr);

    logits_k<<<512, 256, 0, stream>>>(h1f, wr2t, br2, logits);
    topk_scatter_k<<<16, 256, 0, stream>>>(logits, out);
    aux_k<<<1, 256, 0, stream>>>(out + 2 * NEC, out + 2 * NEC + (size_t)N_TOK * E_EXP);
}